// Round 5
// baseline (453.215 us; speedup 1.0000x reference)
//
#include <hip/hip_runtime.h>
#include <hip/hip_fp16.h>
#include <math.h>

#define NB 16
#define NA 720
#define ND 1024
#define NH 512
#define NW 512

#define TW 64      // tile width  (x)
#define TH 8       // tile height (y)
#define PXT 2      // x-subtiles per thread (8x8 lane map: k steps x by 8)
#define NBT 8      // batches per block
#define WINN 68    // window entries (span <= 63|c|+7|s| + 3 ~ 66.4)
#define GROUP 16   // angles per fp16-accumulate group (720 = 45*16)

typedef __fp16 h2vec __attribute__((ext_vector_type(2)));

__device__ __forceinline__ uint32_t pkrtz_u32(float a, float b) {
    union { h2vec h; uint32_t u; } v;
    v.h = __builtin_amdgcn_cvt_pkrtz(a, b);   // one v_cvt_pkrtz_f16_f32
    return v.u;
}
__device__ __forceinline__ __half2 u32_to_h2(uint32_t u) {
    union { uint32_t u; __half2 h; } v; v.u = u; return v.h;
}
__device__ __forceinline__ uint32_t h2_to_u32(__half2 h) {
    union { __half2 h; uint32_t u; } v; v.h = h; return v.u;
}

// ---------------------------------------------------------------------------
// Kernel 0: per-(tile-position, angle) parameter table. 512 positions x 720
// angles x 16B. Entry: (c, s, 511.5-base, bits(a*ND+base)).
// ---------------------------------------------------------------------------
__global__ __launch_bounds__(768) void prep_kernel(float4* __restrict__ ptable) {
    const int a = threadIdx.x;
    const int pos = blockIdx.x;
    if (a >= NA) return;
    const float step = (float)(M_PI / (double)NA);
    float s, c;
    sincosf((float)a * step, &s, &c);
    const int bx = pos & 7, by = pos >> 3;
    const float x0 = (float)(bx * TW) - 255.5f;
    const float x1 = x0 + (float)(TW - 1);
    const float y0 = (float)(by * TH) - 255.5f;
    // s >= 0 for angles in [0, pi): min over y at y0.
    const float tmin = 511.5f + fminf(x0 * c, x1 * c) + y0 * s;
    const int base = (int)floorf(tmin) - 1;
    ptable[pos * NA + a] = make_float4(c, s, 511.5f - (float)base,
                                       __int_as_float(a * ND + base));
}

// ---------------------------------------------------------------------------
// Kernel 1: ramp filter via in-LDS Stockham RADIX-4 FFT (fp32), 5 passes per
// direction, XOR granule swizzle SZ on all LDS indices (R3: -30us).
// R5 change: gather buffer G now stores (f, df) per pair instead of
// (f, f_next): G[duo][a][i] = (f_p2[i], df_p2[i], f_p3[i], df_p3[i]),
// df = f[i+1]-f[i] computed HERE (once per element) instead of per
// pixel-angle in backproj (-2 hsub2/thread-k-angle there).
// ---------------------------------------------------------------------------
#define SZ(i) ((i) ^ (((i) >> 4) & 15))

__device__ __forceinline__ float2 cmul(float2 w, float2 v) {
    return make_float2(w.x * v.x - w.y * v.y, w.x * v.y + w.y * v.x);
}
__device__ __forceinline__ float2 cmulc(float2 w, float2 v) {  // conj(w)*v
    return make_float2(w.x * v.x + w.y * v.y, w.x * v.y - w.y * v.x);
}

__global__ __launch_bounds__(256) void filter_kernel(const float* __restrict__ sino,
                                                     const float* __restrict__ filt,
                                                     uint32_t* __restrict__ packed,
                                                     uint4* __restrict__ gbuf) {
    __shared__ float2 bufA[ND];
    __shared__ float2 bufB[ND];
    __shared__ float2 tw4[768];   // tw4[t] = exp(-2*pi*i*t/ND), t < 3N/4

    const int tid = threadIdx.x;
    const int a = blockIdx.x;       // angle
    const int p = blockIdx.y;       // batch pair
    const float* __restrict__ xa = sino + ((size_t)(2 * p) * NA + a) * ND;
    const float* __restrict__ xb = xa + (size_t)NA * ND;
    uint32_t* __restrict__ yo = packed + ((size_t)(2 * p) * NA + a) * ND;

    #pragma unroll
    for (int i = 0; i < ND; i += 256)
        bufA[SZ(i + tid)] = make_float2(xa[i + tid], xb[i + tid]);
    #pragma unroll
    for (int i = 0; i < 768; i += 256) {
        int m = i + tid;
        float ang = (float)(-2.0 * M_PI / (double)ND) * (float)m;
        float s, c;
        sincosf(ang, &s, &c);
        tw4[SZ(m)] = make_float2(c, s);
    }
    __syncthreads();

    float2* src = bufA;
    float2* dst = bufB;

    // forward FFT: Stockham radix-4, Ns = 1,4,16,64,256
    for (int Ns = 1; Ns < ND; Ns <<= 2) {
        const int j = tid;
        const int m = j & (Ns - 1);
        const int tstep = (ND / 4) / Ns;
        float2 u0 = src[SZ(j)];
        float2 x1 = src[SZ(j + 256)];
        float2 x2 = src[SZ(j + 512)];
        float2 x3 = src[SZ(j + 768)];
        float2 w1 = tw4[SZ(m * tstep)];
        float2 w2 = tw4[SZ(2 * m * tstep)];
        float2 w3 = tw4[SZ(3 * m * tstep)];
        float2 u1 = cmul(w1, x1), u2 = cmul(w2, x2), u3 = cmul(w3, x3);
        float2 A  = make_float2(u0.x + u2.x, u0.y + u2.y);
        float2 Bb = make_float2(u0.x - u2.x, u0.y - u2.y);
        float2 C  = make_float2(u1.x + u3.x, u1.y + u3.y);
        float2 D  = make_float2(u1.x - u3.x, u1.y - u3.y);
        const int d = ((j & ~(Ns - 1)) << 2) + m;
        dst[SZ(d)]          = make_float2(A.x + C.x, A.y + C.y);
        dst[SZ(d + Ns)]     = make_float2(Bb.x + D.y, Bb.y - D.x);   // -i*D
        dst[SZ(d + 2 * Ns)] = make_float2(A.x - C.x, A.y - C.y);
        dst[SZ(d + 3 * Ns)] = make_float2(Bb.x - D.y, Bb.y + D.x);   // +i*D
        __syncthreads();
        float2* tmp = src; src = dst; dst = tmp;
    }

    // multiply by real filter, with 1/ND folded in
    const float SCALE = 1.0f / (float)ND;
    #pragma unroll
    for (int i = 0; i < ND; i += 256) {
        float f = filt[i + tid] * SCALE;
        src[SZ(i + tid)].x *= f;
        src[SZ(i + tid)].y *= f;
    }
    __syncthreads();

    // inverse FFT: conjugated twiddles, y1/y3 swapped (+i/-i)
    for (int Ns = 1; Ns < ND; Ns <<= 2) {
        const int j = tid;
        const int m = j & (Ns - 1);
        const int tstep = (ND / 4) / Ns;
        float2 u0 = src[SZ(j)];
        float2 x1 = src[SZ(j + 256)];
        float2 x2 = src[SZ(j + 512)];
        float2 x3 = src[SZ(j + 768)];
        float2 w1 = tw4[SZ(m * tstep)];
        float2 w2 = tw4[SZ(2 * m * tstep)];
        float2 w3 = tw4[SZ(3 * m * tstep)];
        float2 u1 = cmulc(w1, x1), u2 = cmulc(w2, x2), u3 = cmulc(w3, x3);
        float2 A  = make_float2(u0.x + u2.x, u0.y + u2.y);
        float2 Bb = make_float2(u0.x - u2.x, u0.y - u2.y);
        float2 C  = make_float2(u1.x + u3.x, u1.y + u3.y);
        float2 D  = make_float2(u1.x - u3.x, u1.y - u3.y);
        const int d = ((j & ~(Ns - 1)) << 2) + m;
        dst[SZ(d)]          = make_float2(A.x + C.x, A.y + C.y);
        dst[SZ(d + Ns)]     = make_float2(Bb.x - D.y, Bb.y + D.x);   // +i*D
        dst[SZ(d + 2 * Ns)] = make_float2(A.x - C.x, A.y - C.y);
        dst[SZ(d + 3 * Ns)] = make_float2(Bb.x + D.y, Bb.y - D.x);   // -i*D
        __syncthreads();
        float2* tmp = src; src = dst; dst = tmp;
    }

    const int duo = (p == 2 || p == 3) ? 0 : (p == 6 || p == 7) ? 1 : -1;
    #pragma unroll
    for (int i = 0; i < ND; i += 256) {
        const int idx = i + tid;
        float2 v = src[SZ(idx)];
        uint32_t u = pkrtz_u32(v.x, v.y);
        yo[idx] = u;
        if (gbuf != nullptr && duo >= 0) {
            float2 vn = src[SZ(min(idx + 1, ND - 1))];
            uint32_t un = pkrtz_u32(vn.x, vn.y);
            uint32_t df = h2_to_u32(__hsub2(u32_to_h2(un), u32_to_h2(u)));
            char* e = (char*)(gbuf + ((size_t)duo * NA + a) * ND + idx)
                      + ((p & 1) ? 8 : 0);
            *(uint2*)e = make_uint2(u, df);
        }
    }
}

// ---------------------------------------------------------------------------
// Kernel 2 (R5): hybrid-pipe backprojection with cross-barrier prefetch.
// R4 split batches across the LDS pipe (pairs 4bz+0/1 via win, 1
// ds_read_b128/thread-k) and the TA/L1 pipe (pairs 4bz+2/3 via G, 1
// global_load_dwordx4/thread-k) but regressed 305->360: __syncthreads'
// vmcnt(0) drain exposed ~200cyc L2 latency per phase, and consume-time
// hsub2 grew VALU to 238us. R5 keeps the split and fixes the overlap:
//  1. G-gathers (addresses depend only on ptable, never on staged LDS)
//     are ISSUED one sub-round ahead: issue(a+2,a+3) at top of sub-round
//     A, consumed in sub-round B. i0/wh2 computed once at issue.
//  2. Raw barrier (s_waitcnt lgkmcnt(0) + s_barrier) replaces
//     __syncthreads: global loads stay in flight across barriers (m201
//     pattern); LDS RAW safety via the explicit lgkmcnt drain.
//  3. G stores (f, df): consume is symmetric with the LDS quad, no hsub2.
// Pipe budget at full overlap: LDS ~160us, VALU ~205us, TA ~240us.
// ---------------------------------------------------------------------------
__global__ __launch_bounds__(256, 4) void backproj_kernel(const uint32_t* __restrict__ packed,
                                                          const uint4* __restrict__ gbuf,
                                                          const float4* __restrict__ ptable,
                                                          float* __restrict__ img) {
    // win[ph][i]: pairs 4bz+0, 4bz+1; entry = (fA, dfA, fB, dfB) fp16-packed
    // 4*68*16B = 4352 B
    __shared__ __align__(16) uint4 win[4][WINN];

    const int tid = threadIdx.x;
    const int bx = blockIdx.x, by = blockIdx.y, bz = blockIdx.z;

    const float4* __restrict__ pt = ptable + (size_t)((by << 3) + bx) * NA;
    const uint4* __restrict__ Gb = gbuf + (size_t)bz * NA * ND;

    // staging: threads 0..67 stage pairs 4bz+0 (sbA), 4bz+1 (sbB)
    const bool stg = tid < WINN;
    const uint32_t* __restrict__ sbA =
        packed + (size_t)(2 * (4 * bz)) * NA * ND + tid;
    const uint32_t* __restrict__ sbB = sbA + (size_t)2 * NA * ND;
    uint4* const wptr = &win[0][tid < WINN ? tid : 0];

    // lane map: wave = 8x x 8y; thread's k-subtiles at x = 16*wid + 8k + x7
    const int lane = tid & 63;
    const int wid  = tid >> 6;
    const int tx0  = (wid << 4) + (lane & 7);         // k adds 8
    const int ty   = lane >> 3;                       // 0..7
    const float px  = (float)(bx * TW + tx0) - 255.5f;
    const float pyf = (float)(by * TH + ty)  - 255.5f;

    float accf[8][PXT];
    __half2 hacc01[PXT], hacc23[PXT], hacc45[PXT], hacc67[PXT];
    #pragma unroll
    for (int k = 0; k < PXT; k++) {
        #pragma unroll
        for (int b = 0; b < 8; b++) accf[b][k] = 0.0f;
        hacc01[k] = u32_to_h2(0u); hacc23[k] = u32_to_h2(0u);
        hacc45[k] = u32_to_h2(0u); hacc67[k] = u32_to_h2(0u);
    }

    // raw barrier: drain own LDS ops, sync waves, do NOT drain vmcnt --
    // global loads (G prefetch + staging loads) stay in flight across it.
    auto bar = []() {
        asm volatile("s_waitcnt lgkmcnt(0)" ::: "memory");
        __builtin_amdgcn_s_barrier();
    };

    struct Pre { int i0[PXT]; uint32_t wh[PXT]; uint4 gv[PXT]; };

    auto issue = [&](float4 P) {
        Pre r;
        const float tb = fmaf(px, P.x, fmaf(pyf, P.y, P.z));
        #pragma unroll
        for (int k = 0; k < PXT; k++) {
            float t  = fmaf((float)(8 * k), P.x, tb);
            int   i0 = (int)t;                    // t > 0 -> trunc == floor
#if __has_builtin(__builtin_amdgcn_fractf)
            float w  = __builtin_amdgcn_fractf(t);
#else
            float w  = t - (float)i0;
#endif
            r.i0[k] = i0;
            r.wh[k] = pkrtz_u32(w, w);
            r.gv[k] = Gb[__float_as_int(P.w) + i0];   // TA/L1 pipe, prefetch
        }
        return r;
    };
    auto consume = [&](const Pre& pr, int ph) {
        #pragma unroll
        for (int k = 0; k < PXT; k++) {
            __half2 wh2 = u32_to_h2(pr.wh[k]);
            const uint4 qA = win[ph][pr.i0[k]];       // LDS pipe
            hacc01[k] = __hfma2(wh2, u32_to_h2(qA.y), __hadd2(hacc01[k], u32_to_h2(qA.x)));
            hacc23[k] = __hfma2(wh2, u32_to_h2(qA.w), __hadd2(hacc23[k], u32_to_h2(qA.z)));
            hacc45[k] = __hfma2(wh2, u32_to_h2(pr.gv[k].y), __hadd2(hacc45[k], u32_to_h2(pr.gv[k].x)));
            hacc67[k] = __hfma2(wh2, u32_to_h2(pr.gv[k].w), __hadd2(hacc67[k], u32_to_h2(pr.gv[k].z)));
        }
    };

    auto stage_load = [&](float4 P, uint2& wA, uint2& wB) {
        const int off = __float_as_int(P.w);
        const uint32_t* pa = sbA + off;
        const uint32_t* pb = sbB + off;
        wA = make_uint2(pa[0], pa[1]);
        wB = make_uint2(pb[0], pb[1]);
    };
    auto stage_write = [&](int ph, uint2 wA, uint2 wB) {
        wptr[ph * WINN] = make_uint4(
            wA.x, h2_to_u32(__hsub2(u32_to_h2(wA.y), u32_to_h2(wA.x))),
            wB.x, h2_to_u32(__hsub2(u32_to_h2(wB.y), u32_to_h2(wB.x))));
    };

    // prologue: prefetch G for angles 0,1; stage angles 0,1 into phases 0,1;
    // hold raw staging loads of 2,3
    Pre pA0 = issue(pt[0]);
    Pre pA1 = issue(pt[1]);
    uint2 h2A = make_uint2(0, 0), h2B = make_uint2(0, 0);
    uint2 h3A = make_uint2(0, 0), h3B = make_uint2(0, 0);
    if (stg) {
        uint2 wA, wB;
        stage_load(pt[0], wA, wB);  stage_write(0, wA, wB);
        stage_load(pt[1], wA, wB);  stage_write(1, wA, wB);
        stage_load(pt[2], h2A, h2B);
        stage_load(pt[3], h3A, h3B);
    }
    bar();

    for (int g = 0; g < NA; g += GROUP) {
        #pragma unroll 1
        for (int it = 0; it < GROUP / 4; it++) {
            const int a = g + it * 4;
            // params a..a+7 via uniform s_load (a+4.. clamped; only .w used
            // for addresses of angles that are never computed OOB)
            const float4 P0 = pt[a],     P1 = pt[a + 1];
            const float4 P2 = pt[a + 2], P3 = pt[a + 3];
            const float4 P4 = pt[min(a + 4, NA - 1)], P5 = pt[min(a + 5, NA - 1)];
            const float4 P6 = pt[min(a + 6, NA - 1)], P7 = pt[min(a + 7, NA - 1)];

            // ---- sub-round A: compute a, a+1 (ph 0,1) ----
            Pre pB0 = issue(P2);             // G prefetch for a+2 (sub-round B)
            Pre pB1 = issue(P3);             // G prefetch for a+3
            uint2 l4A = make_uint2(0, 0), l4B = make_uint2(0, 0);
            uint2 l5A = make_uint2(0, 0), l5B = make_uint2(0, 0);
            if (stg) {
                stage_load(P4, l4A, l4B);        // angle a+4 (consumed in B)
                stage_load(P5, l5A, l5B);        // angle a+5
                stage_write(2, h2A, h2B);        // angle a+2 -> ph2
                stage_write(3, h3A, h3B);        // angle a+3 -> ph3
            }
            consume(pA0, 0);
            consume(pA1, 1);
            bar();

            // ---- sub-round B: compute a+2, a+3 (ph 2,3) ----
            Pre pN0 = issue(P4);             // G prefetch for a+4 (next it)
            Pre pN1 = issue(P5);             // G prefetch for a+5
            uint2 l6A = make_uint2(0, 0), l6B = make_uint2(0, 0);
            uint2 l7A = make_uint2(0, 0), l7B = make_uint2(0, 0);
            if (stg) {
                stage_load(P6, l6A, l6B);        // angle a+6 (held to next it)
                stage_load(P7, l7A, l7B);        // angle a+7
                stage_write(0, l4A, l4B);        // angle a+4 -> ph0
                stage_write(1, l5A, l5B);        // angle a+5 -> ph1
            }
            consume(pB0, 2);
            consume(pB1, 3);
            pA0 = pN0; pA1 = pN1;
            h2A = l6A; h2B = l6B; h3A = l7A; h3B = l7B;
            bar();
        }
        // flush fp16 group accumulators into fp32
        #pragma unroll
        for (int k = 0; k < PXT; k++) {
            float2 v01 = __half22float2(hacc01[k]);
            float2 v23 = __half22float2(hacc23[k]);
            float2 v45 = __half22float2(hacc45[k]);
            float2 v67 = __half22float2(hacc67[k]);
            accf[0][k] += v01.x; accf[1][k] += v01.y;
            accf[2][k] += v23.x; accf[3][k] += v23.y;
            accf[4][k] += v45.x; accf[5][k] += v45.y;
            accf[6][k] += v67.x; accf[7][k] += v67.y;
            hacc01[k] = u32_to_h2(0u); hacc23[k] = u32_to_h2(0u);
            hacc45[k] = u32_to_h2(0u); hacc67[k] = u32_to_h2(0u);
        }
    }

    const float SCALE = (float)(M_PI / (double)NA);
    const size_t bstride = (size_t)NH * NW;
    // pixel of k-subtile: row by*TH + ty, col bx*TW + tx0 + 8k
    size_t o0 = (((size_t)(bz * NBT) * NH) + (by * TH + ty)) * NW + (bx * TW + tx0);
    #pragma unroll
    for (int k = 0; k < PXT; k++) {
        #pragma unroll
        for (int b = 0; b < 8; b++)
            img[o0 + (size_t)(8 * k) + (size_t)b * bstride] = accf[b][k] * SCALE;
    }
}

// ---------------------------------------------------------------------------
// Fallback backprojection (R3 version, all pairs via LDS) — used when the
// workspace cannot hold the gather buffer G.
// ---------------------------------------------------------------------------
__global__ __launch_bounds__(256, 4) void backproj_kernel_lds(const uint32_t* __restrict__ packed,
                                                              const float4* __restrict__ ptable,
                                                              float* __restrict__ img) {
    __shared__ __align__(16) uint4 win[2][4][WINN];

    const int tid = threadIdx.x;
    const int bx = blockIdx.x, by = blockIdx.y, bz = blockIdx.z;

    const float4* __restrict__ pt = ptable + (size_t)((by << 3) + bx) * NA;

    const bool stg = tid < 2 * WINN;
    const int sg   = (tid >= WINN) ? 1 : 0;
    const int si   = tid - sg * WINN;
    const uint32_t* __restrict__ sbA =
        packed + (size_t)(2 * (4 * bz + 2 * sg)) * NA * ND + si;
    const uint32_t* __restrict__ sbB = sbA + (size_t)2 * NA * ND;
    uint4* const wptr = &win[sg][0][si];

    const int lane = tid & 63;
    const int wid  = tid >> 6;
    const int tx0  = (wid << 4) + (lane & 7);
    const int ty   = lane >> 3;
    const float px  = (float)(bx * TW + tx0) - 255.5f;
    const float pyf = (float)(by * TH + ty)  - 255.5f;

    float accf[8][PXT];
    __half2 hacc01[PXT], hacc23[PXT], hacc45[PXT], hacc67[PXT];
    #pragma unroll
    for (int k = 0; k < PXT; k++) {
        #pragma unroll
        for (int b = 0; b < 8; b++) accf[b][k] = 0.0f;
        hacc01[k] = u32_to_h2(0u); hacc23[k] = u32_to_h2(0u);
        hacc45[k] = u32_to_h2(0u); hacc67[k] = u32_to_h2(0u);
    }

    auto stage_load = [&](float4 P, uint2& wA, uint2& wB) {
        const int off = __float_as_int(P.w);
        wA = make_uint2(sbA[off], sbA[off + 1]);
        wB = make_uint2(sbB[off], sbB[off + 1]);
    };
    auto stage_write = [&](int ph, uint2 wA, uint2 wB) {
        wptr[ph * WINN] = make_uint4(
            wA.x, h2_to_u32(__hsub2(u32_to_h2(wA.y), u32_to_h2(wA.x))),
            wB.x, h2_to_u32(__hsub2(u32_to_h2(wB.y), u32_to_h2(wB.x))));
    };
    auto compute = [&](float4 P, int ph) {
        const float tb = fmaf(px, P.x, fmaf(pyf, P.y, P.z));
        #pragma unroll
        for (int k = 0; k < PXT; k++) {
            float t  = fmaf((float)(8 * k), P.x, tb);
            int   i0 = (int)t;
#if __has_builtin(__builtin_amdgcn_fractf)
            float w  = __builtin_amdgcn_fractf(t);
#else
            float w  = t - (float)i0;
#endif
            __half2 wh2 = u32_to_h2(pkrtz_u32(w, w));
            const uint4 qA = win[0][ph][i0];
            const uint4 qB = win[1][ph][i0];
            hacc01[k] = __hfma2(wh2, u32_to_h2(qA.y), __hadd2(hacc01[k], u32_to_h2(qA.x)));
            hacc23[k] = __hfma2(wh2, u32_to_h2(qA.w), __hadd2(hacc23[k], u32_to_h2(qA.z)));
            hacc45[k] = __hfma2(wh2, u32_to_h2(qB.y), __hadd2(hacc45[k], u32_to_h2(qB.x)));
            hacc67[k] = __hfma2(wh2, u32_to_h2(qB.w), __hadd2(hacc67[k], u32_to_h2(qB.z)));
        }
    };

    uint2 h2A = make_uint2(0, 0), h2B = make_uint2(0, 0);
    uint2 h3A = make_uint2(0, 0), h3B = make_uint2(0, 0);
    if (stg) {
        uint2 wA, wB;
        stage_load(pt[0], wA, wB);  stage_write(0, wA, wB);
        stage_load(pt[1], wA, wB);  stage_write(1, wA, wB);
        stage_load(pt[2], h2A, h2B);
        stage_load(pt[3], h3A, h3B);
    }
    __syncthreads();

    for (int g = 0; g < NA; g += GROUP) {
        #pragma unroll 1
        for (int it = 0; it < GROUP / 4; it++) {
            const int a = g + it * 4;
            const float4 P0 = pt[a],     P1 = pt[a + 1];
            const float4 P2 = pt[a + 2], P3 = pt[a + 3];
            const float4 P4 = pt[min(a + 4, NA - 1)], P5 = pt[min(a + 5, NA - 1)];
            const float4 P6 = pt[min(a + 6, NA - 1)], P7 = pt[min(a + 7, NA - 1)];

            uint2 l4A = make_uint2(0, 0), l4B = make_uint2(0, 0);
            uint2 l5A = make_uint2(0, 0), l5B = make_uint2(0, 0);
            if (stg) {
                stage_load(P4, l4A, l4B);
                stage_load(P5, l5A, l5B);
                stage_write(2, h2A, h2B);
                stage_write(3, h3A, h3B);
            }
            compute(P0, 0);
            compute(P1, 1);
            __syncthreads();

            uint2 l6A = make_uint2(0, 0), l6B = make_uint2(0, 0);
            uint2 l7A = make_uint2(0, 0), l7B = make_uint2(0, 0);
            if (stg) {
                stage_load(P6, l6A, l6B);
                stage_load(P7, l7A, l7B);
                stage_write(0, l4A, l4B);
                stage_write(1, l5A, l5B);
            }
            compute(P2, 2);
            compute(P3, 3);
            h2A = l6A; h2B = l6B; h3A = l7A; h3B = l7B;
            __syncthreads();
        }
        #pragma unroll
        for (int k = 0; k < PXT; k++) {
            float2 v01 = __half22float2(hacc01[k]);
            float2 v23 = __half22float2(hacc23[k]);
            float2 v45 = __half22float2(hacc45[k]);
            float2 v67 = __half22float2(hacc67[k]);
            accf[0][k] += v01.x; accf[1][k] += v01.y;
            accf[2][k] += v23.x; accf[3][k] += v23.y;
            accf[4][k] += v45.x; accf[5][k] += v45.y;
            accf[6][k] += v67.x; accf[7][k] += v67.y;
            hacc01[k] = u32_to_h2(0u); hacc23[k] = u32_to_h2(0u);
            hacc45[k] = u32_to_h2(0u); hacc67[k] = u32_to_h2(0u);
        }
    }

    const float SCALE = (float)(M_PI / (double)NA);
    const size_t bstride = (size_t)NH * NW;
    size_t o0 = (((size_t)(bz * NBT) * NH) + (by * TH + ty)) * NW + (bx * TW + tx0);
    #pragma unroll
    for (int k = 0; k < PXT; k++) {
        #pragma unroll
        for (int b = 0; b < 8; b++)
            img[o0 + (size_t)(8 * k) + (size_t)b * bstride] = accf[b][k] * SCALE;
    }
}

// ---------------------------------------------------------------------------
extern "C" void kernel_launch(void* const* d_in, const int* in_sizes, int n_in,
                              void* d_out, int out_size, void* d_ws, size_t ws_size,
                              hipStream_t stream) {
    const float* sino = (const float*)d_in[0];
    const float* filt = (const float*)d_in[1];
    float* out = (float*)d_out;

    const size_t pack_bytes = (size_t)NB * NA * ND * sizeof(uint32_t);   // 47.2 MB
    const size_t g_bytes    = (size_t)2 * NA * ND * sizeof(uint4);       // 23.6 MB
    const size_t ptab_bytes = (size_t)512 * NA * sizeof(float4);         //  5.9 MB

    uint32_t* packed;
    uint4* gbuf = nullptr;
    float4* ptable;

    if (ws_size >= pack_bytes + g_bytes + ptab_bytes) {
        packed = (uint32_t*)d_ws;
        gbuf   = (uint4*)((char*)d_ws + pack_bytes);
        ptable = (float4*)((char*)d_ws + pack_bytes + g_bytes);
    } else if (ws_size >= pack_bytes + ptab_bytes) {
        packed = (uint32_t*)d_ws;
        ptable = (float4*)((char*)d_ws + pack_bytes);
    } else {
        // in-place pack into the input (filter writes are block-local);
        // params table in d_ws.
        packed = (uint32_t*)d_in[0];
        ptable = (float4*)d_ws;
    }

    prep_kernel<<<dim3(512), dim3(768), 0, stream>>>(ptable);
    filter_kernel<<<dim3(NA, NB / 2), dim3(256), 0, stream>>>(sino, filt, packed, gbuf);
    if (gbuf != nullptr) {
        backproj_kernel<<<dim3(NW / TW, NH / TH, NB / NBT), dim3(256), 0, stream>>>(packed, gbuf, ptable, out);
    } else {
        backproj_kernel_lds<<<dim3(NW / TW, NH / TH, NB / NBT), dim3(256), 0, stream>>>(packed, ptable, out);
    }
}

// Round 6
// 433.219 us; speedup vs baseline: 1.0462x; 1.0462x over previous
//
#include <hip/hip_runtime.h>
#include <hip/hip_fp16.h>
#include <math.h>

#define NB 16
#define NA 720
#define ND 1024
#define NH 512
#define NW 512

#define TW 64      // tile width  (x)
#define TH 8       // tile height (y)
#define PXT 2      // x-subtiles per thread (8x8 lane map: k steps x by 8)
#define NBT 8      // batches per block
#define WINN 68    // window entries (span <= 63|c|+7|s| + 3 ~ 66.4)
#define GROUP 16   // angles per fp16-accumulate group (720 = 45*16)

typedef __fp16 h2vec __attribute__((ext_vector_type(2)));

__device__ __forceinline__ uint32_t pkrtz_u32(float a, float b) {
    union { h2vec h; uint32_t u; } v;
    v.h = __builtin_amdgcn_cvt_pkrtz(a, b);   // one v_cvt_pkrtz_f16_f32
    return v.u;
}
__device__ __forceinline__ __half2 u32_to_h2(uint32_t u) {
    union { uint32_t u; __half2 h; } v; v.u = u; return v.h;
}
__device__ __forceinline__ uint32_t h2_to_u32(__half2 h) {
    union { __half2 h; uint32_t u; } v; v.h = h; return v.u;
}

// ---------------------------------------------------------------------------
// Kernel 0: per-(tile-position, angle) parameter table. 512 positions x 720
// angles x 16B. Entry: (c, s, 511.5-base, bits(a*ND+base)).
// ---------------------------------------------------------------------------
__global__ __launch_bounds__(768) void prep_kernel(float4* __restrict__ ptable) {
    const int a = threadIdx.x;
    const int pos = blockIdx.x;
    if (a >= NA) return;
    const float step = (float)(M_PI / (double)NA);
    float s, c;
    sincosf((float)a * step, &s, &c);
    const int bx = pos & 7, by = pos >> 3;
    const float x0 = (float)(bx * TW) - 255.5f;
    const float x1 = x0 + (float)(TW - 1);
    const float y0 = (float)(by * TH) - 255.5f;
    // s >= 0 for angles in [0, pi): min over y at y0.
    const float tmin = 511.5f + fminf(x0 * c, x1 * c) + y0 * s;
    const int base = (int)floorf(tmin) - 1;
    ptable[pos * NA + a] = make_float4(c, s, 511.5f - (float)base,
                                       __int_as_float(a * ND + base));
}

// ---------------------------------------------------------------------------
// Kernel 1: ramp filter via in-LDS Stockham RADIX-4 FFT (fp32), 5 passes per
// direction, XOR granule swizzle SZ on all LDS indices (R3: -30us).
// Gather buffer G stores (f, df): G[duo][a][i] = (f_p2, df_p2, f_p3, df_p3),
// df computed once per element here instead of per pixel-angle in backproj.
// ---------------------------------------------------------------------------
#define SZ(i) ((i) ^ (((i) >> 4) & 15))

__device__ __forceinline__ float2 cmul(float2 w, float2 v) {
    return make_float2(w.x * v.x - w.y * v.y, w.x * v.y + w.y * v.x);
}
__device__ __forceinline__ float2 cmulc(float2 w, float2 v) {  // conj(w)*v
    return make_float2(w.x * v.x + w.y * v.y, w.x * v.y - w.y * v.x);
}

__global__ __launch_bounds__(256) void filter_kernel(const float* __restrict__ sino,
                                                     const float* __restrict__ filt,
                                                     uint32_t* __restrict__ packed,
                                                     uint4* __restrict__ gbuf) {
    __shared__ float2 bufA[ND];
    __shared__ float2 bufB[ND];
    __shared__ float2 tw4[768];   // tw4[t] = exp(-2*pi*i*t/ND), t < 3N/4

    const int tid = threadIdx.x;
    const int a = blockIdx.x;       // angle
    const int p = blockIdx.y;       // batch pair
    const float* __restrict__ xa = sino + ((size_t)(2 * p) * NA + a) * ND;
    const float* __restrict__ xb = xa + (size_t)NA * ND;
    uint32_t* __restrict__ yo = packed + ((size_t)(2 * p) * NA + a) * ND;

    #pragma unroll
    for (int i = 0; i < ND; i += 256)
        bufA[SZ(i + tid)] = make_float2(xa[i + tid], xb[i + tid]);
    #pragma unroll
    for (int i = 0; i < 768; i += 256) {
        int m = i + tid;
        float ang = (float)(-2.0 * M_PI / (double)ND) * (float)m;
        float s, c;
        sincosf(ang, &s, &c);
        tw4[SZ(m)] = make_float2(c, s);
    }
    __syncthreads();

    float2* src = bufA;
    float2* dst = bufB;

    // forward FFT: Stockham radix-4, Ns = 1,4,16,64,256
    for (int Ns = 1; Ns < ND; Ns <<= 2) {
        const int j = tid;
        const int m = j & (Ns - 1);
        const int tstep = (ND / 4) / Ns;
        float2 u0 = src[SZ(j)];
        float2 x1 = src[SZ(j + 256)];
        float2 x2 = src[SZ(j + 512)];
        float2 x3 = src[SZ(j + 768)];
        float2 w1 = tw4[SZ(m * tstep)];
        float2 w2 = tw4[SZ(2 * m * tstep)];
        float2 w3 = tw4[SZ(3 * m * tstep)];
        float2 u1 = cmul(w1, x1), u2 = cmul(w2, x2), u3 = cmul(w3, x3);
        float2 A  = make_float2(u0.x + u2.x, u0.y + u2.y);
        float2 Bb = make_float2(u0.x - u2.x, u0.y - u2.y);
        float2 C  = make_float2(u1.x + u3.x, u1.y + u3.y);
        float2 D  = make_float2(u1.x - u3.x, u1.y - u3.y);
        const int d = ((j & ~(Ns - 1)) << 2) + m;
        dst[SZ(d)]          = make_float2(A.x + C.x, A.y + C.y);
        dst[SZ(d + Ns)]     = make_float2(Bb.x + D.y, Bb.y - D.x);   // -i*D
        dst[SZ(d + 2 * Ns)] = make_float2(A.x - C.x, A.y - C.y);
        dst[SZ(d + 3 * Ns)] = make_float2(Bb.x - D.y, Bb.y + D.x);   // +i*D
        __syncthreads();
        float2* tmp = src; src = dst; dst = tmp;
    }

    // multiply by real filter, with 1/ND folded in
    const float SCALE = 1.0f / (float)ND;
    #pragma unroll
    for (int i = 0; i < ND; i += 256) {
        float f = filt[i + tid] * SCALE;
        src[SZ(i + tid)].x *= f;
        src[SZ(i + tid)].y *= f;
    }
    __syncthreads();

    // inverse FFT: conjugated twiddles, y1/y3 swapped (+i/-i)
    for (int Ns = 1; Ns < ND; Ns <<= 2) {
        const int j = tid;
        const int m = j & (Ns - 1);
        const int tstep = (ND / 4) / Ns;
        float2 u0 = src[SZ(j)];
        float2 x1 = src[SZ(j + 256)];
        float2 x2 = src[SZ(j + 512)];
        float2 x3 = src[SZ(j + 768)];
        float2 w1 = tw4[SZ(m * tstep)];
        float2 w2 = tw4[SZ(2 * m * tstep)];
        float2 w3 = tw4[SZ(3 * m * tstep)];
        float2 u1 = cmulc(w1, x1), u2 = cmulc(w2, x2), u3 = cmulc(w3, x3);
        float2 A  = make_float2(u0.x + u2.x, u0.y + u2.y);
        float2 Bb = make_float2(u0.x - u2.x, u0.y - u2.y);
        float2 C  = make_float2(u1.x + u3.x, u1.y + u3.y);
        float2 D  = make_float2(u1.x - u3.x, u1.y - u3.y);
        const int d = ((j & ~(Ns - 1)) << 2) + m;
        dst[SZ(d)]          = make_float2(A.x + C.x, A.y + C.y);
        dst[SZ(d + Ns)]     = make_float2(Bb.x - D.y, Bb.y + D.x);   // +i*D
        dst[SZ(d + 2 * Ns)] = make_float2(A.x - C.x, A.y - C.y);
        dst[SZ(d + 3 * Ns)] = make_float2(Bb.x + D.y, Bb.y - D.x);   // -i*D
        __syncthreads();
        float2* tmp = src; src = dst; dst = tmp;
    }

    const int duo = (p == 2 || p == 3) ? 0 : (p == 6 || p == 7) ? 1 : -1;
    #pragma unroll
    for (int i = 0; i < ND; i += 256) {
        const int idx = i + tid;
        float2 v = src[SZ(idx)];
        uint32_t u = pkrtz_u32(v.x, v.y);
        yo[idx] = u;
        if (gbuf != nullptr && duo >= 0) {
            float2 vn = src[SZ(min(idx + 1, ND - 1))];
            uint32_t un = pkrtz_u32(vn.x, vn.y);
            uint32_t df = h2_to_u32(__hsub2(u32_to_h2(un), u32_to_h2(u)));
            char* e = (char*)(gbuf + ((size_t)duo * NA + a) * ND + idx)
                      + ((p & 1) ? 8 : 0);
            *(uint2*)e = make_uint2(u, df);
        }
    }
}

// ---------------------------------------------------------------------------
// Kernel 2 (R6): hybrid-pipe backprojection, SPILL-PROOF prefetch.
// R4 proved the LDS/TA split works (conflicts & LDS halved) but
// __syncthreads' vmcnt(0) drain exposed L2 latency (360us). R5 proved
// cross-barrier prefetch + raw barrier is right but the Pre-struct pipeline
// state (arrays in a struct, 3 generations live) spilled to scratch:
// WRITE_SIZE 16384->56000 KB, +30us. R6 = R5's schedule with lean state:
//  - pipeline state is EIGHT NAMED uint4s (ga0..nb1), alternated by name
//    between sub-rounds (no struct, no array, no copy-chain);
//  - only gathered DATA is carried; i0/wh recomputed at consume (~6 VALU/k);
//  - raw barrier = s_waitcnt lgkmcnt(0) + s_barrier (globals stay in
//    flight); LDS RAW safety via the lgkmcnt drain.
// Peak live ~90 VGPR < 128 cap @ 4 blocks/CU. Verification signal:
// WRITE_SIZE must return to exactly 16384 KB.
// ---------------------------------------------------------------------------
__global__ __launch_bounds__(256, 4) void backproj_kernel(const uint32_t* __restrict__ packed,
                                                          const uint4* __restrict__ gbuf,
                                                          const float4* __restrict__ ptable,
                                                          float* __restrict__ img) {
    // win[ph][i]: pairs 4bz+0, 4bz+1; entry = (fA, dfA, fB, dfB) fp16-packed
    // 4*68*16B = 4352 B
    __shared__ __align__(16) uint4 win[4][WINN];

    const int tid = threadIdx.x;
    const int bx = blockIdx.x, by = blockIdx.y, bz = blockIdx.z;

    const float4* __restrict__ pt = ptable + (size_t)((by << 3) + bx) * NA;
    const uint4* __restrict__ Gb = gbuf + (size_t)bz * NA * ND;

    // staging: threads 0..67 stage pairs 4bz+0 (sbA), 4bz+1 (sbB)
    const bool stg = tid < WINN;
    const uint32_t* __restrict__ sbA =
        packed + (size_t)(2 * (4 * bz)) * NA * ND + tid;
    const uint32_t* __restrict__ sbB = sbA + (size_t)2 * NA * ND;
    uint4* const wptr = &win[0][tid < WINN ? tid : 0];

    // lane map: wave = 8x x 8y; thread's k-subtiles at x = 16*wid + 8k + x7
    const int lane = tid & 63;
    const int wid  = tid >> 6;
    const int tx0  = (wid << 4) + (lane & 7);         // k adds 8
    const int ty   = lane >> 3;                       // 0..7
    const float px  = (float)(bx * TW + tx0) - 255.5f;
    const float pyf = (float)(by * TH + ty)  - 255.5f;

    float accf[8][PXT];
    __half2 hacc01[PXT], hacc23[PXT], hacc45[PXT], hacc67[PXT];
    #pragma unroll
    for (int k = 0; k < PXT; k++) {
        #pragma unroll
        for (int b = 0; b < 8; b++) accf[b][k] = 0.0f;
        hacc01[k] = u32_to_h2(0u); hacc23[k] = u32_to_h2(0u);
        hacc45[k] = u32_to_h2(0u); hacc67[k] = u32_to_h2(0u);
    }

    // raw barrier: drain own LDS ops, sync waves, do NOT drain vmcnt --
    // global loads (G prefetch + staging loads) stay in flight across it.
    auto bar = []() {
        asm volatile("s_waitcnt lgkmcnt(0)" ::: "memory");
        __builtin_amdgcn_s_barrier();
    };

    // issue both G gathers for one angle into two NAMED uint4 regs
    auto prefetch = [&](float4 P, uint4& g0, uint4& g1) {
        const float tb = fmaf(px, P.x, fmaf(pyf, P.y, P.z));
        const int off = __float_as_int(P.w);
        g0 = Gb[off + (int)tb];
        g1 = Gb[off + (int)fmaf(8.0f, P.x, tb)];
    };
    // consume one angle: LDS quad + the two prefetched G quads
    auto consume = [&](float4 P, int ph, uint4 g0, uint4 g1) {
        const float tb = fmaf(px, P.x, fmaf(pyf, P.y, P.z));
        #pragma unroll
        for (int k = 0; k < PXT; k++) {
            float t  = (k == 0) ? tb : fmaf(8.0f, P.x, tb);
            int   i0 = (int)t;                    // t > 0 -> trunc == floor
#if __has_builtin(__builtin_amdgcn_fractf)
            float w  = __builtin_amdgcn_fractf(t);
#else
            float w  = t - (float)i0;
#endif
            __half2 wh2 = u32_to_h2(pkrtz_u32(w, w));
            const uint4 qA = win[ph][i0];                 // LDS pipe
            const uint4 g  = (k == 0) ? g0 : g1;          // prefetched TA data
            hacc01[k] = __hfma2(wh2, u32_to_h2(qA.y), __hadd2(hacc01[k], u32_to_h2(qA.x)));
            hacc23[k] = __hfma2(wh2, u32_to_h2(qA.w), __hadd2(hacc23[k], u32_to_h2(qA.z)));
            hacc45[k] = __hfma2(wh2, u32_to_h2(g.y),  __hadd2(hacc45[k], u32_to_h2(g.x)));
            hacc67[k] = __hfma2(wh2, u32_to_h2(g.w),  __hadd2(hacc67[k], u32_to_h2(g.z)));
        }
    };

    auto stage_load = [&](float4 P, uint2& wA, uint2& wB) {
        const int off = __float_as_int(P.w);
        const uint32_t* pa = sbA + off;
        const uint32_t* pb = sbB + off;
        wA = make_uint2(pa[0], pa[1]);
        wB = make_uint2(pb[0], pb[1]);
    };
    auto stage_write = [&](int ph, uint2 wA, uint2 wB) {
        wptr[ph * WINN] = make_uint4(
            wA.x, h2_to_u32(__hsub2(u32_to_h2(wA.y), u32_to_h2(wA.x))),
            wB.x, h2_to_u32(__hsub2(u32_to_h2(wB.y), u32_to_h2(wB.x))));
    };

    // pipeline state: named regs only (spill-proof)
    uint4 ga0, ga1, gb0, gb1;   // consumed in sub-round A (angles a, a+1)
    uint4 na0, na1, nb0, nb1;   // consumed in sub-round B (angles a+2, a+3)

    // prologue: prefetch G for angles 0,1; stage angles 0,1 into phases 0,1;
    // hold raw staging loads of 2,3
    prefetch(pt[0], ga0, ga1);
    prefetch(pt[1], gb0, gb1);
    uint2 h2A = make_uint2(0, 0), h2B = make_uint2(0, 0);
    uint2 h3A = make_uint2(0, 0), h3B = make_uint2(0, 0);
    if (stg) {
        uint2 wA, wB;
        stage_load(pt[0], wA, wB);  stage_write(0, wA, wB);
        stage_load(pt[1], wA, wB);  stage_write(1, wA, wB);
        stage_load(pt[2], h2A, h2B);
        stage_load(pt[3], h3A, h3B);
    }
    bar();

    for (int g = 0; g < NA; g += GROUP) {
        #pragma unroll 1
        for (int it = 0; it < GROUP / 4; it++) {
            const int a = g + it * 4;
            // params a..a+7 via uniform s_load (a+4.. clamped; only .w used
            // for addresses of angles that are never computed OOB)
            const float4 P0 = pt[a],     P1 = pt[a + 1];
            const float4 P2 = pt[a + 2], P3 = pt[a + 3];
            const float4 P4 = pt[min(a + 4, NA - 1)], P5 = pt[min(a + 5, NA - 1)];
            const float4 P6 = pt[min(a + 6, NA - 1)], P7 = pt[min(a + 7, NA - 1)];

            // ---- sub-round A: consume a, a+1 (ph 0,1); prefetch a+2,a+3 ----
            prefetch(P2, na0, na1);
            prefetch(P3, nb0, nb1);
            uint2 l4A = make_uint2(0, 0), l4B = make_uint2(0, 0);
            uint2 l5A = make_uint2(0, 0), l5B = make_uint2(0, 0);
            if (stg) {
                stage_load(P4, l4A, l4B);        // angle a+4 (consumed in B)
                stage_load(P5, l5A, l5B);        // angle a+5
                stage_write(2, h2A, h2B);        // angle a+2 -> ph2
                stage_write(3, h3A, h3B);        // angle a+3 -> ph3
            }
            consume(P0, 0, ga0, ga1);
            consume(P1, 1, gb0, gb1);
            bar();

            // ---- sub-round B: consume a+2, a+3 (ph 2,3); prefetch a+4,a+5 ----
            prefetch(P4, ga0, ga1);              // for next iteration's A
            prefetch(P5, gb0, gb1);
            uint2 l6A = make_uint2(0, 0), l6B = make_uint2(0, 0);
            uint2 l7A = make_uint2(0, 0), l7B = make_uint2(0, 0);
            if (stg) {
                stage_load(P6, l6A, l6B);        // angle a+6 (held to next it)
                stage_load(P7, l7A, l7B);        // angle a+7
                stage_write(0, l4A, l4B);        // angle a+4 -> ph0
                stage_write(1, l5A, l5B);        // angle a+5 -> ph1
            }
            consume(P2, 2, na0, na1);
            consume(P3, 3, nb0, nb1);
            h2A = l6A; h2B = l6B; h3A = l7A; h3B = l7B;
            bar();
        }
        // flush fp16 group accumulators into fp32
        #pragma unroll
        for (int k = 0; k < PXT; k++) {
            float2 v01 = __half22float2(hacc01[k]);
            float2 v23 = __half22float2(hacc23[k]);
            float2 v45 = __half22float2(hacc45[k]);
            float2 v67 = __half22float2(hacc67[k]);
            accf[0][k] += v01.x; accf[1][k] += v01.y;
            accf[2][k] += v23.x; accf[3][k] += v23.y;
            accf[4][k] += v45.x; accf[5][k] += v45.y;
            accf[6][k] += v67.x; accf[7][k] += v67.y;
            hacc01[k] = u32_to_h2(0u); hacc23[k] = u32_to_h2(0u);
            hacc45[k] = u32_to_h2(0u); hacc67[k] = u32_to_h2(0u);
        }
    }

    const float SCALE = (float)(M_PI / (double)NA);
    const size_t bstride = (size_t)NH * NW;
    // pixel of k-subtile: row by*TH + ty, col bx*TW + tx0 + 8k
    size_t o0 = (((size_t)(bz * NBT) * NH) + (by * TH + ty)) * NW + (bx * TW + tx0);
    #pragma unroll
    for (int k = 0; k < PXT; k++) {
        #pragma unroll
        for (int b = 0; b < 8; b++)
            img[o0 + (size_t)(8 * k) + (size_t)b * bstride] = accf[b][k] * SCALE;
    }
}

// ---------------------------------------------------------------------------
// Fallback backprojection (R3 version, all pairs via LDS) — used when the
// workspace cannot hold the gather buffer G.
// ---------------------------------------------------------------------------
__global__ __launch_bounds__(256, 4) void backproj_kernel_lds(const uint32_t* __restrict__ packed,
                                                              const float4* __restrict__ ptable,
                                                              float* __restrict__ img) {
    __shared__ __align__(16) uint4 win[2][4][WINN];

    const int tid = threadIdx.x;
    const int bx = blockIdx.x, by = blockIdx.y, bz = blockIdx.z;

    const float4* __restrict__ pt = ptable + (size_t)((by << 3) + bx) * NA;

    const bool stg = tid < 2 * WINN;
    const int sg   = (tid >= WINN) ? 1 : 0;
    const int si   = tid - sg * WINN;
    const uint32_t* __restrict__ sbA =
        packed + (size_t)(2 * (4 * bz + 2 * sg)) * NA * ND + si;
    const uint32_t* __restrict__ sbB = sbA + (size_t)2 * NA * ND;
    uint4* const wptr = &win[sg][0][si];

    const int lane = tid & 63;
    const int wid  = tid >> 6;
    const int tx0  = (wid << 4) + (lane & 7);
    const int ty   = lane >> 3;
    const float px  = (float)(bx * TW + tx0) - 255.5f;
    const float pyf = (float)(by * TH + ty)  - 255.5f;

    float accf[8][PXT];
    __half2 hacc01[PXT], hacc23[PXT], hacc45[PXT], hacc67[PXT];
    #pragma unroll
    for (int k = 0; k < PXT; k++) {
        #pragma unroll
        for (int b = 0; b < 8; b++) accf[b][k] = 0.0f;
        hacc01[k] = u32_to_h2(0u); hacc23[k] = u32_to_h2(0u);
        hacc45[k] = u32_to_h2(0u); hacc67[k] = u32_to_h2(0u);
    }

    auto stage_load = [&](float4 P, uint2& wA, uint2& wB) {
        const int off = __float_as_int(P.w);
        wA = make_uint2(sbA[off], sbA[off + 1]);
        wB = make_uint2(sbB[off], sbB[off + 1]);
    };
    auto stage_write = [&](int ph, uint2 wA, uint2 wB) {
        wptr[ph * WINN] = make_uint4(
            wA.x, h2_to_u32(__hsub2(u32_to_h2(wA.y), u32_to_h2(wA.x))),
            wB.x, h2_to_u32(__hsub2(u32_to_h2(wB.y), u32_to_h2(wB.x))));
    };
    auto compute = [&](float4 P, int ph) {
        const float tb = fmaf(px, P.x, fmaf(pyf, P.y, P.z));
        #pragma unroll
        for (int k = 0; k < PXT; k++) {
            float t  = fmaf((float)(8 * k), P.x, tb);
            int   i0 = (int)t;
#if __has_builtin(__builtin_amdgcn_fractf)
            float w  = __builtin_amdgcn_fractf(t);
#else
            float w  = t - (float)i0;
#endif
            __half2 wh2 = u32_to_h2(pkrtz_u32(w, w));
            const uint4 qA = win[0][ph][i0];
            const uint4 qB = win[1][ph][i0];
            hacc01[k] = __hfma2(wh2, u32_to_h2(qA.y), __hadd2(hacc01[k], u32_to_h2(qA.x)));
            hacc23[k] = __hfma2(wh2, u32_to_h2(qA.w), __hadd2(hacc23[k], u32_to_h2(qA.z)));
            hacc45[k] = __hfma2(wh2, u32_to_h2(qB.y), __hadd2(hacc45[k], u32_to_h2(qB.x)));
            hacc67[k] = __hfma2(wh2, u32_to_h2(qB.w), __hadd2(hacc67[k], u32_to_h2(qB.z)));
        }
    };

    uint2 h2A = make_uint2(0, 0), h2B = make_uint2(0, 0);
    uint2 h3A = make_uint2(0, 0), h3B = make_uint2(0, 0);
    if (stg) {
        uint2 wA, wB;
        stage_load(pt[0], wA, wB);  stage_write(0, wA, wB);
        stage_load(pt[1], wA, wB);  stage_write(1, wA, wB);
        stage_load(pt[2], h2A, h2B);
        stage_load(pt[3], h3A, h3B);
    }
    __syncthreads();

    for (int g = 0; g < NA; g += GROUP) {
        #pragma unroll 1
        for (int it = 0; it < GROUP / 4; it++) {
            const int a = g + it * 4;
            const float4 P0 = pt[a],     P1 = pt[a + 1];
            const float4 P2 = pt[a + 2], P3 = pt[a + 3];
            const float4 P4 = pt[min(a + 4, NA - 1)], P5 = pt[min(a + 5, NA - 1)];
            const float4 P6 = pt[min(a + 6, NA - 1)], P7 = pt[min(a + 7, NA - 1)];

            uint2 l4A = make_uint2(0, 0), l4B = make_uint2(0, 0);
            uint2 l5A = make_uint2(0, 0), l5B = make_uint2(0, 0);
            if (stg) {
                stage_load(P4, l4A, l4B);
                stage_load(P5, l5A, l5B);
                stage_write(2, h2A, h2B);
                stage_write(3, h3A, h3B);
            }
            compute(P0, 0);
            compute(P1, 1);
            __syncthreads();

            uint2 l6A = make_uint2(0, 0), l6B = make_uint2(0, 0);
            uint2 l7A = make_uint2(0, 0), l7B = make_uint2(0, 0);
            if (stg) {
                stage_load(P6, l6A, l6B);
                stage_load(P7, l7A, l7B);
                stage_write(0, l4A, l4B);
                stage_write(1, l5A, l5B);
            }
            compute(P2, 2);
            compute(P3, 3);
            h2A = l6A; h2B = l6B; h3A = l7A; h3B = l7B;
            __syncthreads();
        }
        #pragma unroll
        for (int k = 0; k < PXT; k++) {
            float2 v01 = __half22float2(hacc01[k]);
            float2 v23 = __half22float2(hacc23[k]);
            float2 v45 = __half22float2(hacc45[k]);
            float2 v67 = __half22float2(hacc67[k]);
            accf[0][k] += v01.x; accf[1][k] += v01.y;
            accf[2][k] += v23.x; accf[3][k] += v23.y;
            accf[4][k] += v45.x; accf[5][k] += v45.y;
            accf[6][k] += v67.x; accf[7][k] += v67.y;
            hacc01[k] = u32_to_h2(0u); hacc23[k] = u32_to_h2(0u);
            hacc45[k] = u32_to_h2(0u); hacc67[k] = u32_to_h2(0u);
        }
    }

    const float SCALE = (float)(M_PI / (double)NA);
    const size_t bstride = (size_t)NH * NW;
    size_t o0 = (((size_t)(bz * NBT) * NH) + (by * TH + ty)) * NW + (bx * TW + tx0);
    #pragma unroll
    for (int k = 0; k < PXT; k++) {
        #pragma unroll
        for (int b = 0; b < 8; b++)
            img[o0 + (size_t)(8 * k) + (size_t)b * bstride] = accf[b][k] * SCALE;
    }
}

// ---------------------------------------------------------------------------
extern "C" void kernel_launch(void* const* d_in, const int* in_sizes, int n_in,
                              void* d_out, int out_size, void* d_ws, size_t ws_size,
                              hipStream_t stream) {
    const float* sino = (const float*)d_in[0];
    const float* filt = (const float*)d_in[1];
    float* out = (float*)d_out;

    const size_t pack_bytes = (size_t)NB * NA * ND * sizeof(uint32_t);   // 47.2 MB
    const size_t g_bytes    = (size_t)2 * NA * ND * sizeof(uint4);       // 23.6 MB
    const size_t ptab_bytes = (size_t)512 * NA * sizeof(float4);         //  5.9 MB

    uint32_t* packed;
    uint4* gbuf = nullptr;
    float4* ptable;

    if (ws_size >= pack_bytes + g_bytes + ptab_bytes) {
        packed = (uint32_t*)d_ws;
        gbuf   = (uint4*)((char*)d_ws + pack_bytes);
        ptable = (float4*)((char*)d_ws + pack_bytes + g_bytes);
    } else if (ws_size >= pack_bytes + ptab_bytes) {
        packed = (uint32_t*)d_ws;
        ptable = (float4*)((char*)d_ws + pack_bytes);
    } else {
        // in-place pack into the input (filter writes are block-local);
        // params table in d_ws.
        packed = (uint32_t*)d_in[0];
        ptable = (float4*)d_ws;
    }

    prep_kernel<<<dim3(512), dim3(768), 0, stream>>>(ptable);
    filter_kernel<<<dim3(NA, NB / 2), dim3(256), 0, stream>>>(sino, filt, packed, gbuf);
    if (gbuf != nullptr) {
        backproj_kernel<<<dim3(NW / TW, NH / TH, NB / NBT), dim3(256), 0, stream>>>(packed, gbuf, ptable, out);
    } else {
        backproj_kernel_lds<<<dim3(NW / TW, NH / TH, NB / NBT), dim3(256), 0, stream>>>(packed, ptable, out);
    }
}

// Round 7
// 366.007 us; speedup vs baseline: 1.2383x; 1.1836x over previous
//
#include <hip/hip_runtime.h>
#include <hip/hip_fp16.h>
#include <math.h>

#define NB 16
#define NA 720
#define ND 1024
#define NH 512
#define NW 512

#define TW 64      // tile width  (x)
#define TH 8       // tile height (y)
#define PXT 2      // x-subtiles per thread (8x8 lane map: k steps x by 8)
#define NBT 8      // batches per block
#define WINN 68    // window entries (span <= 63|c|+7|s| + 3 ~ 66.4)

typedef __fp16 h2vec __attribute__((ext_vector_type(2)));

__device__ __forceinline__ uint32_t pkrtz_u32(float a, float b) {
    union { h2vec h; uint32_t u; } v;
    v.h = __builtin_amdgcn_cvt_pkrtz(a, b);   // one v_cvt_pkrtz_f16_f32
    return v.u;
}
__device__ __forceinline__ __half2 u32_to_h2(uint32_t u) {
    union { uint32_t u; __half2 h; } v; v.u = u; return v.h;
}
__device__ __forceinline__ uint32_t h2_to_u32(__half2 h) {
    union { __half2 h; uint32_t u; } v; v.h = h; return v.u;
}

// ---------------------------------------------------------------------------
// Kernel 0: per-(tile-position, angle) parameter table (512 pos x 720 ang x
// 16B; entry (c, s, 511.5-base, bits(a*ND+base))) + global FFT twiddle table
// (block 512: tw[m] = exp(-2*pi*i*m/1024), m < 768) so the filter loads
// twiddles from L2 instead of 3 sincosf per thread per block.
// ---------------------------------------------------------------------------
__global__ __launch_bounds__(768) void prep_kernel(float4* __restrict__ ptable,
                                                   float2* __restrict__ twg) {
    const int a = threadIdx.x;
    const int pos = blockIdx.x;
    if (pos == 512) {
        float ang = (float)(-2.0 * M_PI / 1024.0) * (float)a;
        float s, c;
        sincosf(ang, &s, &c);
        twg[a] = make_float2(c, s);
        return;
    }
    if (a >= NA) return;
    const float step = (float)(M_PI / (double)NA);
    float s, c;
    sincosf((float)a * step, &s, &c);
    const int bx = pos & 7, by = pos >> 3;
    const float x0 = (float)(bx * TW) - 255.5f;
    const float x1 = x0 + (float)(TW - 1);
    const float y0 = (float)(by * TH) - 255.5f;
    // s >= 0 for angles in [0, pi): min over y at y0.
    const float tmin = 511.5f + fminf(x0 * c, x1 * c) + y0 * s;
    const int base = (int)floorf(tmin) - 1;
    ptable[pos * NA + a] = make_float4(c, s, 511.5f - (float)base,
                                       __int_as_float(a * ND + base));
}

// ---------------------------------------------------------------------------
// Kernel 1: ramp filter via in-LDS Stockham RADIX-4 FFT (fp32), 5 passes per
// direction, XOR granule swizzle SZ on all LDS indices (R3: -30us). R7:
// twiddles loaded from the prep-built global table (no per-block sincosf);
// gather-buffer epilogue removed (hybrid backproj abandoned after R4-R6:
// TA-path VALU addressing cost > LDS savings).
// Pairs the two rows of a BATCH-PAIR at the SAME angle: z = x_2p + i*x_2p+1;
// real even filter -> Y = filt*Z; IFFT -> Re = batch 2p, Im = batch 2p+1.
// Output fp16-PACKED u32 into the row slot of batch 2p; 1/ND folded in.
// ---------------------------------------------------------------------------
#define SZ(i) ((i) ^ (((i) >> 4) & 15))

__device__ __forceinline__ float2 cmul(float2 w, float2 v) {
    return make_float2(w.x * v.x - w.y * v.y, w.x * v.y + w.y * v.x);
}
__device__ __forceinline__ float2 cmulc(float2 w, float2 v) {  // conj(w)*v
    return make_float2(w.x * v.x + w.y * v.y, w.x * v.y - w.y * v.x);
}

__global__ __launch_bounds__(256) void filter_kernel(const float* __restrict__ sino,
                                                     const float* __restrict__ filt,
                                                     const float2* __restrict__ twg,
                                                     uint32_t* __restrict__ packed) {
    __shared__ float2 bufA[ND];
    __shared__ float2 bufB[ND];
    __shared__ float2 tw4[768];   // tw4[t] = exp(-2*pi*i*t/ND), t < 3N/4

    const int tid = threadIdx.x;
    const int a = blockIdx.x;       // angle
    const int p = blockIdx.y;       // batch pair
    const float* __restrict__ xa = sino + ((size_t)(2 * p) * NA + a) * ND;
    const float* __restrict__ xb = xa + (size_t)NA * ND;
    uint32_t* __restrict__ yo = packed + ((size_t)(2 * p) * NA + a) * ND;

    #pragma unroll
    for (int i = 0; i < ND; i += 256)
        bufA[SZ(i + tid)] = make_float2(xa[i + tid], xb[i + tid]);
    #pragma unroll
    for (int i = 0; i < 768; i += 256) {
        int m = i + tid;
        tw4[SZ(m)] = twg[m];
    }
    __syncthreads();

    float2* src = bufA;
    float2* dst = bufB;

    // forward FFT: Stockham radix-4, Ns = 1,4,16,64,256
    for (int Ns = 1; Ns < ND; Ns <<= 2) {
        const int j = tid;
        const int m = j & (Ns - 1);
        const int tstep = (ND / 4) / Ns;
        float2 u0 = src[SZ(j)];
        float2 x1 = src[SZ(j + 256)];
        float2 x2 = src[SZ(j + 512)];
        float2 x3 = src[SZ(j + 768)];
        float2 w1 = tw4[SZ(m * tstep)];
        float2 w2 = tw4[SZ(2 * m * tstep)];
        float2 w3 = tw4[SZ(3 * m * tstep)];
        float2 u1 = cmul(w1, x1), u2 = cmul(w2, x2), u3 = cmul(w3, x3);
        float2 A  = make_float2(u0.x + u2.x, u0.y + u2.y);
        float2 Bb = make_float2(u0.x - u2.x, u0.y - u2.y);
        float2 C  = make_float2(u1.x + u3.x, u1.y + u3.y);
        float2 D  = make_float2(u1.x - u3.x, u1.y - u3.y);
        const int d = ((j & ~(Ns - 1)) << 2) + m;
        dst[SZ(d)]          = make_float2(A.x + C.x, A.y + C.y);
        dst[SZ(d + Ns)]     = make_float2(Bb.x + D.y, Bb.y - D.x);   // -i*D
        dst[SZ(d + 2 * Ns)] = make_float2(A.x - C.x, A.y - C.y);
        dst[SZ(d + 3 * Ns)] = make_float2(Bb.x - D.y, Bb.y + D.x);   // +i*D
        __syncthreads();
        float2* tmp = src; src = dst; dst = tmp;
    }

    // multiply by real filter, with 1/ND folded in
    const float SCALE = 1.0f / (float)ND;
    #pragma unroll
    for (int i = 0; i < ND; i += 256) {
        float f = filt[i + tid] * SCALE;
        src[SZ(i + tid)].x *= f;
        src[SZ(i + tid)].y *= f;
    }
    __syncthreads();

    // inverse FFT: conjugated twiddles, y1/y3 swapped (+i/-i)
    for (int Ns = 1; Ns < ND; Ns <<= 2) {
        const int j = tid;
        const int m = j & (Ns - 1);
        const int tstep = (ND / 4) / Ns;
        float2 u0 = src[SZ(j)];
        float2 x1 = src[SZ(j + 256)];
        float2 x2 = src[SZ(j + 512)];
        float2 x3 = src[SZ(j + 768)];
        float2 w1 = tw4[SZ(m * tstep)];
        float2 w2 = tw4[SZ(2 * m * tstep)];
        float2 w3 = tw4[SZ(3 * m * tstep)];
        float2 u1 = cmulc(w1, x1), u2 = cmulc(w2, x2), u3 = cmulc(w3, x3);
        float2 A  = make_float2(u0.x + u2.x, u0.y + u2.y);
        float2 Bb = make_float2(u0.x - u2.x, u0.y - u2.y);
        float2 C  = make_float2(u1.x + u3.x, u1.y + u3.y);
        float2 D  = make_float2(u1.x - u3.x, u1.y - u3.y);
        const int d = ((j & ~(Ns - 1)) << 2) + m;
        dst[SZ(d)]          = make_float2(A.x + C.x, A.y + C.y);
        dst[SZ(d + Ns)]     = make_float2(Bb.x - D.y, Bb.y + D.x);   // +i*D
        dst[SZ(d + 2 * Ns)] = make_float2(A.x - C.x, A.y - C.y);
        dst[SZ(d + 3 * Ns)] = make_float2(Bb.x + D.y, Bb.y - D.x);   // -i*D
        __syncthreads();
        float2* tmp = src; src = dst; dst = tmp;
    }

    #pragma unroll
    for (int i = 0; i < ND; i += 256) {
        float2 v = src[SZ(i + tid)];
        yo[i + tid] = pkrtz_u32(v.x, v.y);
    }
}

// ---------------------------------------------------------------------------
// Kernel 2 (R7): pure-LDS backprojection (R3 structure — hybrid abandoned)
// with HALVED sync overhead:
//  - 8-phase window win[2][8][WINN] (two ping-pong banks of 4 phases,
//    17.4 KB): ONE barrier per 4 angles (180/block vs R3's 360).
//  - raw barrier = s_waitcnt lgkmcnt(0) + s_barrier (R6-validated):
//    staging global-loads stay in flight across barriers; LDS RAW safety
//    via the lgkmcnt drain.
//  - held staging data in 16 NAMED uint2 regs (R5 spill lesson: no
//    arrays/structs); loads for angles a+8..a+11 issued at top of round r,
//    written to the free bank in round r+1, consumed in round r+2 -> a full
//    round (~600cyc) of latency cover.
// Round r: write held a+4..a+7 -> bank (r+1)&1; issue loads a+8..a+11;
// consume a..a+3 from bank r&1; flush fp16 acc every 4 rounds; barrier.
// 64x8 tile x 8 batches, 8x8 lane map, 1024 blocks -> 4/CU.
// ---------------------------------------------------------------------------
__global__ __launch_bounds__(256, 4) void backproj_kernel(const uint32_t* __restrict__ packed,
                                                          const float4* __restrict__ ptable,
                                                          float* __restrict__ img) {
    // win[sg][ph][i]: sg=0 -> batches 0..3, sg=1 -> batches 4..7
    // entry = (fA, dfA, fB, dfB) fp16-packed; 2*8*68*16B = 17408 B
    __shared__ __align__(16) uint4 win[2][8][WINN];

    const int tid = threadIdx.x;
    const int bx = blockIdx.x, by = blockIdx.y, bz = blockIdx.z;

    const float4* __restrict__ pt = ptable + (size_t)((by << 3) + bx) * NA;

    // staging: threads 0..135; sg selects batch quad (0: b0..3 / 1: b4..7)
    const bool stg = tid < 2 * WINN;
    const int sg   = (tid >= WINN) ? 1 : 0;
    const int si   = tid - sg * WINN;
    const uint32_t* __restrict__ sbA =
        packed + (size_t)(2 * (4 * bz + 2 * sg)) * NA * ND + si;
    const uint32_t* __restrict__ sbB = sbA + (size_t)2 * NA * ND;
    uint4* const wptr = &win[sg][0][si];

    // lane map: wave = 8x x 8y; thread's k-subtiles at x = 16*wid + 8k + x7
    const int lane = tid & 63;
    const int wid  = tid >> 6;
    const int tx0  = (wid << 4) + (lane & 7);         // k adds 8
    const int ty   = lane >> 3;                       // 0..7
    const float px  = (float)(bx * TW + tx0) - 255.5f;
    const float pyf = (float)(by * TH + ty)  - 255.5f;

    float accf[8][PXT];
    __half2 hacc01[PXT], hacc23[PXT], hacc45[PXT], hacc67[PXT];
    #pragma unroll
    for (int k = 0; k < PXT; k++) {
        #pragma unroll
        for (int b = 0; b < 8; b++) accf[b][k] = 0.0f;
        hacc01[k] = u32_to_h2(0u); hacc23[k] = u32_to_h2(0u);
        hacc45[k] = u32_to_h2(0u); hacc67[k] = u32_to_h2(0u);
    }

    // raw barrier: drain own LDS ops, sync waves, do NOT drain vmcnt --
    // staging global loads stay in flight across it (R6-validated).
    auto bar = []() {
        asm volatile("s_waitcnt lgkmcnt(0)" ::: "memory");
        __builtin_amdgcn_s_barrier();
    };

    auto stage_load = [&](float4 P, uint2& wA, uint2& wB) {
        const int off = __float_as_int(P.w);
        const uint32_t* pa = sbA + off;
        const uint32_t* pb = sbB + off;
        wA = make_uint2(pa[0], pa[1]);
        wB = make_uint2(pb[0], pb[1]);
    };
    auto stage_write = [&](int ph, uint2 wA, uint2 wB) {
        wptr[ph * WINN] = make_uint4(
            wA.x, h2_to_u32(__hsub2(u32_to_h2(wA.y), u32_to_h2(wA.x))),
            wB.x, h2_to_u32(__hsub2(u32_to_h2(wB.y), u32_to_h2(wB.x))));
    };
    auto consume = [&](float4 P, int ph) {
        const float tb = fmaf(px, P.x, fmaf(pyf, P.y, P.z));
        #pragma unroll
        for (int k = 0; k < PXT; k++) {
            float t  = fmaf((float)(8 * k), P.x, tb);  // x-step 8 per k
            int   i0 = (int)t;                    // t > 0 -> trunc == floor
#if __has_builtin(__builtin_amdgcn_fractf)
            float w  = __builtin_amdgcn_fractf(t);
#else
            float w  = t - (float)i0;
#endif
            __half2 wh2 = u32_to_h2(pkrtz_u32(w, w));   // one pkrtz
            const uint4 qA = win[0][ph][i0];            // ds_read_b128
            const uint4 qB = win[1][ph][i0];            // ds_read_b128
            hacc01[k] = __hfma2(wh2, u32_to_h2(qA.y), __hadd2(hacc01[k], u32_to_h2(qA.x)));
            hacc23[k] = __hfma2(wh2, u32_to_h2(qA.w), __hadd2(hacc23[k], u32_to_h2(qA.z)));
            hacc45[k] = __hfma2(wh2, u32_to_h2(qB.y), __hadd2(hacc45[k], u32_to_h2(qB.x)));
            hacc67[k] = __hfma2(wh2, u32_to_h2(qB.w), __hadd2(hacc67[k], u32_to_h2(qB.z)));
        }
    };

    // held staging data: angles 4r+4..4r+7, loaded in round r-1 (named regs)
    uint2 h0A = make_uint2(0, 0), h0B = make_uint2(0, 0);
    uint2 h1A = make_uint2(0, 0), h1B = make_uint2(0, 0);
    uint2 h2A = make_uint2(0, 0), h2B = make_uint2(0, 0);
    uint2 h3A = make_uint2(0, 0), h3B = make_uint2(0, 0);

    // prologue: stage angles 0..3 into bank0 (ph 0..3); hold loads of 4..7
    if (stg) {
        uint2 wA, wB;
        stage_load(pt[0], wA, wB);  stage_write(0, wA, wB);
        stage_load(pt[1], wA, wB);  stage_write(1, wA, wB);
        stage_load(pt[2], wA, wB);  stage_write(2, wA, wB);
        stage_load(pt[3], wA, wB);  stage_write(3, wA, wB);
        stage_load(pt[4], h0A, h0B);
        stage_load(pt[5], h1A, h1B);
        stage_load(pt[6], h2A, h2B);
        stage_load(pt[7], h3A, h3B);
    }
    bar();

    #pragma unroll 1
    for (int r = 0; r < NA / 4; ++r) {
        const int a = 4 * r;
        const int cb = (r & 1) * 4;        // consume bank phase base
        const int ob = cb ^ 4;             // write bank phase base
        const float4 P0 = pt[a],     P1 = pt[a + 1];
        const float4 P2 = pt[a + 2], P3 = pt[a + 3];

        if (stg) {
            // write held angles a+4..a+7 into the free bank (consumed next round)
            stage_write(ob + 0, h0A, h0B);
            stage_write(ob + 1, h1A, h1B);
            stage_write(ob + 2, h2A, h2B);
            stage_write(ob + 3, h3A, h3B);
            // issue loads for angles a+8..a+11 (written in round r+1)
            stage_load(pt[min(a + 8,  NA - 1)], h0A, h0B);
            stage_load(pt[min(a + 9,  NA - 1)], h1A, h1B);
            stage_load(pt[min(a + 10, NA - 1)], h2A, h2B);
            stage_load(pt[min(a + 11, NA - 1)], h3A, h3B);
        }
        consume(P0, cb + 0);
        consume(P1, cb + 1);
        consume(P2, cb + 2);
        consume(P3, cb + 3);

        // flush fp16 group accumulators into fp32 every 4 rounds (16 angles)
        if ((r & 3) == 3) {
            #pragma unroll
            for (int k = 0; k < PXT; k++) {
                float2 v01 = __half22float2(hacc01[k]);
                float2 v23 = __half22float2(hacc23[k]);
                float2 v45 = __half22float2(hacc45[k]);
                float2 v67 = __half22float2(hacc67[k]);
                accf[0][k] += v01.x; accf[1][k] += v01.y;
                accf[2][k] += v23.x; accf[3][k] += v23.y;
                accf[4][k] += v45.x; accf[5][k] += v45.y;
                accf[6][k] += v67.x; accf[7][k] += v67.y;
                hacc01[k] = u32_to_h2(0u); hacc23[k] = u32_to_h2(0u);
                hacc45[k] = u32_to_h2(0u); hacc67[k] = u32_to_h2(0u);
            }
        }
        bar();
    }

    const float SCALE = (float)(M_PI / (double)NA);
    const size_t bstride = (size_t)NH * NW;
    // pixel of k-subtile: row by*TH + ty, col bx*TW + tx0 + 8k
    size_t o0 = (((size_t)(bz * NBT) * NH) + (by * TH + ty)) * NW + (bx * TW + tx0);
    #pragma unroll
    for (int k = 0; k < PXT; k++) {
        #pragma unroll
        for (int b = 0; b < 8; b++)
            img[o0 + (size_t)(8 * k) + (size_t)b * bstride] = accf[b][k] * SCALE;
    }
}

// ---------------------------------------------------------------------------
extern "C" void kernel_launch(void* const* d_in, const int* in_sizes, int n_in,
                              void* d_out, int out_size, void* d_ws, size_t ws_size,
                              hipStream_t stream) {
    const float* sino = (const float*)d_in[0];
    const float* filt = (const float*)d_in[1];
    float* out = (float*)d_out;

    const size_t pack_bytes = (size_t)NB * NA * ND * sizeof(uint32_t);   // 47.2 MB
    const size_t ptab_bytes = (size_t)512 * NA * sizeof(float4);         //  5.9 MB
    const size_t twg_bytes  = (size_t)768 * sizeof(float2);              //  6 KB

    uint32_t* packed;
    float4* ptable;
    float2* twg;

    if (ws_size >= pack_bytes + ptab_bytes + twg_bytes) {
        packed = (uint32_t*)d_ws;
        ptable = (float4*)((char*)d_ws + pack_bytes);
        twg    = (float2*)((char*)d_ws + pack_bytes + ptab_bytes);
    } else {
        // in-place pack into the input (filter writes are block-local);
        // params table + twiddles in d_ws.
        packed = (uint32_t*)d_in[0];
        ptable = (float4*)d_ws;
        twg    = (float2*)((char*)d_ws + ptab_bytes);
    }

    prep_kernel<<<dim3(513), dim3(768), 0, stream>>>(ptable, twg);
    filter_kernel<<<dim3(NA, NB / 2), dim3(256), 0, stream>>>(sino, filt, twg, packed);
    backproj_kernel<<<dim3(NW / TW, NH / TH, NB / NBT), dim3(256), 0, stream>>>(packed, ptable, out);
}

// Round 8
// 356.739 us; speedup vs baseline: 1.2704x; 1.0260x over previous
//
#include <hip/hip_runtime.h>
#include <hip/hip_fp16.h>
#include <math.h>

#define NB 16
#define NA 720
#define ND 1024
#define NH 512
#define NW 512

#define TW 32      // tile width  (x)
#define TH 8       // tile height (y)
#define NBT 8      // batches per block
#define WINN 36    // window entries (span <= sqrt(31^2+7^2)+3 ~ 34.8)

typedef __fp16 h2vec __attribute__((ext_vector_type(2)));

__device__ __forceinline__ uint32_t pkrtz_u32(float a, float b) {
    union { h2vec h; uint32_t u; } v;
    v.h = __builtin_amdgcn_cvt_pkrtz(a, b);   // one v_cvt_pkrtz_f16_f32
    return v.u;
}
__device__ __forceinline__ __half2 u32_to_h2(uint32_t u) {
    union { uint32_t u; __half2 h; } v; v.u = u; return v.h;
}
__device__ __forceinline__ uint32_t h2_to_u32(__half2 h) {
    union { __half2 h; uint32_t u; } v; v.h = h; return v.u;
}

// ---------------------------------------------------------------------------
// Kernel 0: per-(tile-position, angle) parameter table (1024 pos x 720 ang x
// 16B; entry (c, s, 511.5-base, bits(a*ND+base))) for the 32x8 tile grid
// (bx 0..15, by 0..63) + global FFT twiddle table (block 1024:
// tw[m] = exp(-2*pi*i*m/1024), m < 768).
// ---------------------------------------------------------------------------
__global__ __launch_bounds__(768) void prep_kernel(float4* __restrict__ ptable,
                                                   float2* __restrict__ twg) {
    const int a = threadIdx.x;
    const int pos = blockIdx.x;
    if (pos == 1024) {
        float ang = (float)(-2.0 * M_PI / 1024.0) * (float)a;
        float s, c;
        sincosf(ang, &s, &c);
        twg[a] = make_float2(c, s);
        return;
    }
    if (a >= NA) return;
    const float step = (float)(M_PI / (double)NA);
    float s, c;
    sincosf((float)a * step, &s, &c);
    const int bx = pos & 15, by = pos >> 4;
    const float x0 = (float)(bx * TW) - 255.5f;
    const float x1 = x0 + (float)(TW - 1);
    const float y0 = (float)(by * TH) - 255.5f;
    // s >= 0 for angles in [0, pi): min over y at y0.
    const float tmin = 511.5f + fminf(x0 * c, x1 * c) + y0 * s;
    const int base = (int)floorf(tmin) - 1;
    ptable[pos * NA + a] = make_float4(c, s, 511.5f - (float)base,
                                       __int_as_float(a * ND + base));
}

// ---------------------------------------------------------------------------
// Kernel 1: ramp filter via in-LDS Stockham RADIX-4 FFT (fp32), 5 passes per
// direction, XOR granule swizzle SZ on all LDS indices; twiddles loaded from
// the prep-built global table. Pairs the two rows of a BATCH-PAIR at the
// SAME angle: z = x_2p + i*x_2p+1; real even filter -> Y = filt*Z; IFFT ->
// Re = batch 2p, Im = batch 2p+1. Output fp16-PACKED u32 into the row slot
// of batch 2p; 1/ND folded in.
// ---------------------------------------------------------------------------
#define SZ(i) ((i) ^ (((i) >> 4) & 15))

__device__ __forceinline__ float2 cmul(float2 w, float2 v) {
    return make_float2(w.x * v.x - w.y * v.y, w.x * v.y + w.y * v.x);
}
__device__ __forceinline__ float2 cmulc(float2 w, float2 v) {  // conj(w)*v
    return make_float2(w.x * v.x + w.y * v.y, w.x * v.y - w.y * v.x);
}

__global__ __launch_bounds__(256) void filter_kernel(const float* __restrict__ sino,
                                                     const float* __restrict__ filt,
                                                     const float2* __restrict__ twg,
                                                     uint32_t* __restrict__ packed) {
    __shared__ float2 bufA[ND];
    __shared__ float2 bufB[ND];
    __shared__ float2 tw4[768];   // tw4[t] = exp(-2*pi*i*t/ND), t < 3N/4

    const int tid = threadIdx.x;
    const int a = blockIdx.x;       // angle
    const int p = blockIdx.y;       // batch pair
    const float* __restrict__ xa = sino + ((size_t)(2 * p) * NA + a) * ND;
    const float* __restrict__ xb = xa + (size_t)NA * ND;
    uint32_t* __restrict__ yo = packed + ((size_t)(2 * p) * NA + a) * ND;

    #pragma unroll
    for (int i = 0; i < ND; i += 256)
        bufA[SZ(i + tid)] = make_float2(xa[i + tid], xb[i + tid]);
    #pragma unroll
    for (int i = 0; i < 768; i += 256) {
        int m = i + tid;
        tw4[SZ(m)] = twg[m];
    }
    __syncthreads();

    float2* src = bufA;
    float2* dst = bufB;

    // forward FFT: Stockham radix-4, Ns = 1,4,16,64,256
    for (int Ns = 1; Ns < ND; Ns <<= 2) {
        const int j = tid;
        const int m = j & (Ns - 1);
        const int tstep = (ND / 4) / Ns;
        float2 u0 = src[SZ(j)];
        float2 x1 = src[SZ(j + 256)];
        float2 x2 = src[SZ(j + 512)];
        float2 x3 = src[SZ(j + 768)];
        float2 w1 = tw4[SZ(m * tstep)];
        float2 w2 = tw4[SZ(2 * m * tstep)];
        float2 w3 = tw4[SZ(3 * m * tstep)];
        float2 u1 = cmul(w1, x1), u2 = cmul(w2, x2), u3 = cmul(w3, x3);
        float2 A  = make_float2(u0.x + u2.x, u0.y + u2.y);
        float2 Bb = make_float2(u0.x - u2.x, u0.y - u2.y);
        float2 C  = make_float2(u1.x + u3.x, u1.y + u3.y);
        float2 D  = make_float2(u1.x - u3.x, u1.y - u3.y);
        const int d = ((j & ~(Ns - 1)) << 2) + m;
        dst[SZ(d)]          = make_float2(A.x + C.x, A.y + C.y);
        dst[SZ(d + Ns)]     = make_float2(Bb.x + D.y, Bb.y - D.x);   // -i*D
        dst[SZ(d + 2 * Ns)] = make_float2(A.x - C.x, A.y - C.y);
        dst[SZ(d + 3 * Ns)] = make_float2(Bb.x - D.y, Bb.y + D.x);   // +i*D
        __syncthreads();
        float2* tmp = src; src = dst; dst = tmp;
    }

    // multiply by real filter, with 1/ND folded in
    const float SCALE = 1.0f / (float)ND;
    #pragma unroll
    for (int i = 0; i < ND; i += 256) {
        float f = filt[i + tid] * SCALE;
        src[SZ(i + tid)].x *= f;
        src[SZ(i + tid)].y *= f;
    }
    __syncthreads();

    // inverse FFT: conjugated twiddles, y1/y3 swapped (+i/-i)
    for (int Ns = 1; Ns < ND; Ns <<= 2) {
        const int j = tid;
        const int m = j & (Ns - 1);
        const int tstep = (ND / 4) / Ns;
        float2 u0 = src[SZ(j)];
        float2 x1 = src[SZ(j + 256)];
        float2 x2 = src[SZ(j + 512)];
        float2 x3 = src[SZ(j + 768)];
        float2 w1 = tw4[SZ(m * tstep)];
        float2 w2 = tw4[SZ(2 * m * tstep)];
        float2 w3 = tw4[SZ(3 * m * tstep)];
        float2 u1 = cmulc(w1, x1), u2 = cmulc(w2, x2), u3 = cmulc(w3, x3);
        float2 A  = make_float2(u0.x + u2.x, u0.y + u2.y);
        float2 Bb = make_float2(u0.x - u2.x, u0.y - u2.y);
        float2 C  = make_float2(u1.x + u3.x, u1.y + u3.y);
        float2 D  = make_float2(u1.x - u3.x, u1.y - u3.y);
        const int d = ((j & ~(Ns - 1)) << 2) + m;
        dst[SZ(d)]          = make_float2(A.x + C.x, A.y + C.y);
        dst[SZ(d + Ns)]     = make_float2(Bb.x - D.y, Bb.y + D.x);   // +i*D
        dst[SZ(d + 2 * Ns)] = make_float2(A.x - C.x, A.y - C.y);
        dst[SZ(d + 3 * Ns)] = make_float2(Bb.x + D.y, Bb.y - D.x);   // -i*D
        __syncthreads();
        float2* tmp = src; src = dst; dst = tmp;
    }

    #pragma unroll
    for (int i = 0; i < ND; i += 256) {
        float2 v = src[SZ(i + tid)];
        yo[i + tid] = pkrtz_u32(v.x, v.y);
    }
}

// ---------------------------------------------------------------------------
// Kernel 2 (R8): pure-LDS backprojection, OCCUPANCY-DOUBLED.
// R7 analysis: LDS b128 gather issue is the binding pipe (64 wave-ops x
// 1024B per CU-angle ~ 259us at the measured ~85 B/cyc single-issue rate =
// 88% of the 295us measured), conflicts now negligible (9.5e5), VALU slack
// (176us), occupancy only 36% (4 blocks/CU, grid-capped). The 85 B/cyc is a
// LOW-CONCURRENCY issue rate; LDS HW peak is 128 B/cyc. R8 doubles resident
// waves without changing per-pixel arithmetic or total LDS bytes:
//   tile 64x8 -> 32x8 (1 pixel/thread), WINN 68 -> 36, LDS 17408 -> 9216 B,
//   grid 1024 -> 2048 blocks = 8 blocks/CU, __launch_bounds__(256,8).
// Same 8x x 8y lane map (wave = 8x8 patch, span 8|c|+8|s|), same 2
// ds_read_b128/thread-angle, same 8-phase ping-pong window + raw
// lgkmcnt-only barrier (180/block), same named-reg held staging.
// ---------------------------------------------------------------------------
__global__ __launch_bounds__(256, 8) void backproj_kernel(const uint32_t* __restrict__ packed,
                                                          const float4* __restrict__ ptable,
                                                          float* __restrict__ img) {
    // win[sg][ph][i]: sg=0 -> batches 0..3, sg=1 -> batches 4..7
    // entry = (fA, dfA, fB, dfB) fp16-packed; 2*8*36*16B = 9216 B
    __shared__ __align__(16) uint4 win[2][8][WINN];

    const int tid = threadIdx.x;
    const int bx = blockIdx.x, by = blockIdx.y, bz = blockIdx.z;

    const float4* __restrict__ pt = ptable + (size_t)((by << 4) + bx) * NA;

    // staging: threads 0..71; sg selects batch quad (0: b0..3 / 1: b4..7)
    const bool stg = tid < 2 * WINN;
    const int sg   = (tid >= WINN) ? 1 : 0;
    const int si   = tid - sg * WINN;
    const uint32_t* __restrict__ sbA =
        packed + (size_t)(2 * (4 * bz + 2 * sg)) * NA * ND + si;
    const uint32_t* __restrict__ sbB = sbA + (size_t)2 * NA * ND;
    uint4* const wptr = &win[sg][0][si];

    // lane map: wave = 8x x 8y patch; 4 waves tile x
    const int lane = tid & 63;
    const int wid  = tid >> 6;
    const int tx   = (wid << 3) + (lane & 7);
    const int ty   = lane >> 3;                       // 0..7
    const float px  = (float)(bx * TW + tx) - 255.5f;
    const float pyf = (float)(by * TH + ty) - 255.5f;

    float accf[8];
    __half2 hacc01, hacc23, hacc45, hacc67;
    #pragma unroll
    for (int b = 0; b < 8; b++) accf[b] = 0.0f;
    hacc01 = u32_to_h2(0u); hacc23 = u32_to_h2(0u);
    hacc45 = u32_to_h2(0u); hacc67 = u32_to_h2(0u);

    // raw barrier: drain own LDS ops, sync waves, do NOT drain vmcnt --
    // staging global loads stay in flight across it (R6/R7-validated).
    auto bar = []() {
        asm volatile("s_waitcnt lgkmcnt(0)" ::: "memory");
        __builtin_amdgcn_s_barrier();
    };

    auto stage_load = [&](float4 P, uint2& wA, uint2& wB) {
        const int off = __float_as_int(P.w);
        const uint32_t* pa = sbA + off;
        const uint32_t* pb = sbB + off;
        wA = make_uint2(pa[0], pa[1]);
        wB = make_uint2(pb[0], pb[1]);
    };
    auto stage_write = [&](int ph, uint2 wA, uint2 wB) {
        wptr[ph * WINN] = make_uint4(
            wA.x, h2_to_u32(__hsub2(u32_to_h2(wA.y), u32_to_h2(wA.x))),
            wB.x, h2_to_u32(__hsub2(u32_to_h2(wB.y), u32_to_h2(wB.x))));
    };
    auto consume = [&](float4 P, int ph) {
        const float t = fmaf(px, P.x, fmaf(pyf, P.y, P.z));
        const int i0 = (int)t;                    // t > 0 -> trunc == floor
#if __has_builtin(__builtin_amdgcn_fractf)
        float w = __builtin_amdgcn_fractf(t);
#else
        float w = t - (float)i0;
#endif
        __half2 wh2 = u32_to_h2(pkrtz_u32(w, w));   // one pkrtz
        const uint4 qA = win[0][ph][i0];            // ds_read_b128
        const uint4 qB = win[1][ph][i0];            // ds_read_b128 (+imm off)
        hacc01 = __hfma2(wh2, u32_to_h2(qA.y), __hadd2(hacc01, u32_to_h2(qA.x)));
        hacc23 = __hfma2(wh2, u32_to_h2(qA.w), __hadd2(hacc23, u32_to_h2(qA.z)));
        hacc45 = __hfma2(wh2, u32_to_h2(qB.y), __hadd2(hacc45, u32_to_h2(qB.x)));
        hacc67 = __hfma2(wh2, u32_to_h2(qB.w), __hadd2(hacc67, u32_to_h2(qB.z)));
    };

    // held staging data: angles 4r+4..4r+7, loaded in round r-1 (named regs)
    uint2 h0A = make_uint2(0, 0), h0B = make_uint2(0, 0);
    uint2 h1A = make_uint2(0, 0), h1B = make_uint2(0, 0);
    uint2 h2A = make_uint2(0, 0), h2B = make_uint2(0, 0);
    uint2 h3A = make_uint2(0, 0), h3B = make_uint2(0, 0);

    // prologue: stage angles 0..3 into bank0 (ph 0..3); hold loads of 4..7
    if (stg) {
        uint2 wA, wB;
        stage_load(pt[0], wA, wB);  stage_write(0, wA, wB);
        stage_load(pt[1], wA, wB);  stage_write(1, wA, wB);
        stage_load(pt[2], wA, wB);  stage_write(2, wA, wB);
        stage_load(pt[3], wA, wB);  stage_write(3, wA, wB);
        stage_load(pt[4], h0A, h0B);
        stage_load(pt[5], h1A, h1B);
        stage_load(pt[6], h2A, h2B);
        stage_load(pt[7], h3A, h3B);
    }
    bar();

    #pragma unroll 1
    for (int r = 0; r < NA / 4; ++r) {
        const int a = 4 * r;
        const int cb = (r & 1) * 4;        // consume bank phase base
        const int ob = cb ^ 4;             // write bank phase base
        const float4 P0 = pt[a],     P1 = pt[a + 1];
        const float4 P2 = pt[a + 2], P3 = pt[a + 3];

        if (stg) {
            // write held angles a+4..a+7 into the free bank (consumed next round)
            stage_write(ob + 0, h0A, h0B);
            stage_write(ob + 1, h1A, h1B);
            stage_write(ob + 2, h2A, h2B);
            stage_write(ob + 3, h3A, h3B);
            // issue loads for angles a+8..a+11 (written in round r+1)
            stage_load(pt[min(a + 8,  NA - 1)], h0A, h0B);
            stage_load(pt[min(a + 9,  NA - 1)], h1A, h1B);
            stage_load(pt[min(a + 10, NA - 1)], h2A, h2B);
            stage_load(pt[min(a + 11, NA - 1)], h3A, h3B);
        }
        consume(P0, cb + 0);
        consume(P1, cb + 1);
        consume(P2, cb + 2);
        consume(P3, cb + 3);

        // flush fp16 group accumulators into fp32 every 4 rounds (16 angles)
        if ((r & 3) == 3) {
            float2 v01 = __half22float2(hacc01);
            float2 v23 = __half22float2(hacc23);
            float2 v45 = __half22float2(hacc45);
            float2 v67 = __half22float2(hacc67);
            accf[0] += v01.x; accf[1] += v01.y;
            accf[2] += v23.x; accf[3] += v23.y;
            accf[4] += v45.x; accf[5] += v45.y;
            accf[6] += v67.x; accf[7] += v67.y;
            hacc01 = u32_to_h2(0u); hacc23 = u32_to_h2(0u);
            hacc45 = u32_to_h2(0u); hacc67 = u32_to_h2(0u);
        }
        bar();
    }

    const float SCALE = (float)(M_PI / (double)NA);
    const size_t bstride = (size_t)NH * NW;
    size_t o0 = (((size_t)(bz * NBT) * NH) + (by * TH + ty)) * NW + (bx * TW + tx);
    #pragma unroll
    for (int b = 0; b < 8; b++)
        img[o0 + (size_t)b * bstride] = accf[b] * SCALE;
}

// ---------------------------------------------------------------------------
extern "C" void kernel_launch(void* const* d_in, const int* in_sizes, int n_in,
                              void* d_out, int out_size, void* d_ws, size_t ws_size,
                              hipStream_t stream) {
    const float* sino = (const float*)d_in[0];
    const float* filt = (const float*)d_in[1];
    float* out = (float*)d_out;

    const size_t pack_bytes = (size_t)NB * NA * ND * sizeof(uint32_t);   // 47.2 MB
    const size_t ptab_bytes = (size_t)1024 * NA * sizeof(float4);        // 11.8 MB
    const size_t twg_bytes  = (size_t)768 * sizeof(float2);              //  6 KB

    uint32_t* packed;
    float4* ptable;
    float2* twg;

    if (ws_size >= pack_bytes + ptab_bytes + twg_bytes) {
        packed = (uint32_t*)d_ws;
        ptable = (float4*)((char*)d_ws + pack_bytes);
        twg    = (float2*)((char*)d_ws + pack_bytes + ptab_bytes);
    } else {
        // in-place pack into the input (filter writes are block-local);
        // params table + twiddles in d_ws.
        packed = (uint32_t*)d_in[0];
        ptable = (float4*)d_ws;
        twg    = (float2*)((char*)d_ws + ptab_bytes);
    }

    prep_kernel<<<dim3(1025), dim3(768), 0, stream>>>(ptable, twg);
    filter_kernel<<<dim3(NA, NB / 2), dim3(256), 0, stream>>>(sino, filt, twg, packed);
    backproj_kernel<<<dim3(NW / TW, NH / TH, NB / NBT), dim3(256), 0, stream>>>(packed, ptable, out);
}

// Round 9
// 341.990 us; speedup vs baseline: 1.3252x; 1.0431x over previous
//
#include <hip/hip_runtime.h>
#include <hip/hip_fp16.h>
#include <math.h>

#define NB 16
#define NA 720
#define ND 1024
#define NH 512
#define NW 512

#define TW 32      // tile width  (x)
#define TH 8       // tile height (y)
#define NBT 8      // batches per block
#define WREG 64    // padded window entries per (bank,phase,sg) — gload_lds
                   // writes full-wave 64x16B; real span <= 36

typedef __fp16 h2vec __attribute__((ext_vector_type(2)));

__device__ __forceinline__ uint32_t pkrtz_u32(float a, float b) {
    union { h2vec h; uint32_t u; } v;
    v.h = __builtin_amdgcn_cvt_pkrtz(a, b);   // one v_cvt_pkrtz_f16_f32
    return v.u;
}
__device__ __forceinline__ __half2 u32_to_h2(uint32_t u) {
    union { uint32_t u; __half2 h; } v; v.u = u; return v.h;
}
__device__ __forceinline__ uint32_t h2_to_u32(__half2 h) {
    union { __half2 h; uint32_t u; } v; v.h = h; return v.u;
}

// ---------------------------------------------------------------------------
// Kernel 0: per-(tile-position, angle) parameter table (1024 pos x 720 ang,
// entry (c, s, 511.5-base, bits(a*ND+base))) for the 32x8 tile grid + global
// FFT twiddle table (block 1024). t = px*c+py*s+511.5 in [150, 873] for all
// pixels/angles -> Gq row index a*ND+base+lane stays in [0, ND*NA) even with
// the 64-entry padded staging read (base+63 <= 935).
// ---------------------------------------------------------------------------
__global__ __launch_bounds__(768) void prep_kernel(float4* __restrict__ ptable,
                                                   float2* __restrict__ twg) {
    const int a = threadIdx.x;
    const int pos = blockIdx.x;
    if (pos == 1024) {
        float ang = (float)(-2.0 * M_PI / 1024.0) * (float)a;
        float s, c;
        sincosf(ang, &s, &c);
        twg[a] = make_float2(c, s);
        return;
    }
    if (a >= NA) return;
    const float step = (float)(M_PI / (double)NA);
    float s, c;
    sincosf((float)a * step, &s, &c);
    const int bx = pos & 15, by = pos >> 4;
    const float x0 = (float)(bx * TW) - 255.5f;
    const float x1 = x0 + (float)(TW - 1);
    const float y0 = (float)(by * TH) - 255.5f;
    // s >= 0 for angles in [0, pi): min over y at y0.
    const float tmin = 511.5f + fminf(x0 * c, x1 * c) + y0 * s;
    const int base = (int)floorf(tmin) - 1;
    ptable[pos * NA + a] = make_float4(c, s, 511.5f - (float)base,
                                       __int_as_float(a * ND + base));
}

// ---------------------------------------------------------------------------
// Kernel 1: ramp filter via in-LDS Stockham RADIX-4 FFT (fp32), 5 passes per
// direction, XOR granule swizzle SZ, twiddles from the prep-built table.
// Pairs the two rows of a BATCH-PAIR at the SAME angle: z = x_2p + i*x_2p+1;
// real even filter -> Y = filt*Z; IFFT -> Re = batch 2p, Im = batch 2p+1.
// R9 epilogue (main path): writes the GATHER-READY quad buffer
//   Gq[q][a][i] = (f_{2q}[i], df_{2q}[i], f_{2q+1}[i], df_{2q+1}[i])
// (16B entries; block p writes the (p&1) uint2 half — R4/R5-proven). This is
// what lets backproj stage via global_load_lds with ZERO transform.
// Fallback path (gq==null): packed fp16-pair rows as before.
// ---------------------------------------------------------------------------
#define SZ(i) ((i) ^ (((i) >> 4) & 15))

__device__ __forceinline__ float2 cmul(float2 w, float2 v) {
    return make_float2(w.x * v.x - w.y * v.y, w.x * v.y + w.y * v.x);
}
__device__ __forceinline__ float2 cmulc(float2 w, float2 v) {  // conj(w)*v
    return make_float2(w.x * v.x + w.y * v.y, w.x * v.y - w.y * v.x);
}

__global__ __launch_bounds__(256) void filter_kernel(const float* __restrict__ sino,
                                                     const float* __restrict__ filt,
                                                     const float2* __restrict__ twg,
                                                     uint4* __restrict__ gq,
                                                     uint32_t* __restrict__ packed) {
    __shared__ float2 bufA[ND];
    __shared__ float2 bufB[ND];
    __shared__ float2 tw4[768];   // tw4[t] = exp(-2*pi*i*t/ND), t < 3N/4

    const int tid = threadIdx.x;
    const int a = blockIdx.x;       // angle
    const int p = blockIdx.y;       // batch pair
    const float* __restrict__ xa = sino + ((size_t)(2 * p) * NA + a) * ND;
    const float* __restrict__ xb = xa + (size_t)NA * ND;

    #pragma unroll
    for (int i = 0; i < ND; i += 256)
        bufA[SZ(i + tid)] = make_float2(xa[i + tid], xb[i + tid]);
    #pragma unroll
    for (int i = 0; i < 768; i += 256) {
        int m = i + tid;
        tw4[SZ(m)] = twg[m];
    }
    __syncthreads();

    float2* src = bufA;
    float2* dst = bufB;

    // forward FFT: Stockham radix-4, Ns = 1,4,16,64,256
    for (int Ns = 1; Ns < ND; Ns <<= 2) {
        const int j = tid;
        const int m = j & (Ns - 1);
        const int tstep = (ND / 4) / Ns;
        float2 u0 = src[SZ(j)];
        float2 x1 = src[SZ(j + 256)];
        float2 x2 = src[SZ(j + 512)];
        float2 x3 = src[SZ(j + 768)];
        float2 w1 = tw4[SZ(m * tstep)];
        float2 w2 = tw4[SZ(2 * m * tstep)];
        float2 w3 = tw4[SZ(3 * m * tstep)];
        float2 u1 = cmul(w1, x1), u2 = cmul(w2, x2), u3 = cmul(w3, x3);
        float2 A  = make_float2(u0.x + u2.x, u0.y + u2.y);
        float2 Bb = make_float2(u0.x - u2.x, u0.y - u2.y);
        float2 C  = make_float2(u1.x + u3.x, u1.y + u3.y);
        float2 D  = make_float2(u1.x - u3.x, u1.y - u3.y);
        const int d = ((j & ~(Ns - 1)) << 2) + m;
        dst[SZ(d)]          = make_float2(A.x + C.x, A.y + C.y);
        dst[SZ(d + Ns)]     = make_float2(Bb.x + D.y, Bb.y - D.x);   // -i*D
        dst[SZ(d + 2 * Ns)] = make_float2(A.x - C.x, A.y - C.y);
        dst[SZ(d + 3 * Ns)] = make_float2(Bb.x - D.y, Bb.y + D.x);   // +i*D
        __syncthreads();
        float2* tmp = src; src = dst; dst = tmp;
    }

    // multiply by real filter, with 1/ND folded in
    const float SCALE = 1.0f / (float)ND;
    #pragma unroll
    for (int i = 0; i < ND; i += 256) {
        float f = filt[i + tid] * SCALE;
        src[SZ(i + tid)].x *= f;
        src[SZ(i + tid)].y *= f;
    }
    __syncthreads();

    // inverse FFT: conjugated twiddles, y1/y3 swapped (+i/-i)
    for (int Ns = 1; Ns < ND; Ns <<= 2) {
        const int j = tid;
        const int m = j & (Ns - 1);
        const int tstep = (ND / 4) / Ns;
        float2 u0 = src[SZ(j)];
        float2 x1 = src[SZ(j + 256)];
        float2 x2 = src[SZ(j + 512)];
        float2 x3 = src[SZ(j + 768)];
        float2 w1 = tw4[SZ(m * tstep)];
        float2 w2 = tw4[SZ(2 * m * tstep)];
        float2 w3 = tw4[SZ(3 * m * tstep)];
        float2 u1 = cmulc(w1, x1), u2 = cmulc(w2, x2), u3 = cmulc(w3, x3);
        float2 A  = make_float2(u0.x + u2.x, u0.y + u2.y);
        float2 Bb = make_float2(u0.x - u2.x, u0.y - u2.y);
        float2 C  = make_float2(u1.x + u3.x, u1.y + u3.y);
        float2 D  = make_float2(u1.x - u3.x, u1.y - u3.y);
        const int d = ((j & ~(Ns - 1)) << 2) + m;
        dst[SZ(d)]          = make_float2(A.x + C.x, A.y + C.y);
        dst[SZ(d + Ns)]     = make_float2(Bb.x - D.y, Bb.y + D.x);   // +i*D
        dst[SZ(d + 2 * Ns)] = make_float2(A.x - C.x, A.y - C.y);
        dst[SZ(d + 3 * Ns)] = make_float2(Bb.x + D.y, Bb.y - D.x);   // -i*D
        __syncthreads();
        float2* tmp = src; src = dst; dst = tmp;
    }

    if (gq != nullptr) {
        // gather-ready quad entries: block p fills the (p&1) half of quad p>>1
        char* gb = (char*)(gq + ((size_t)(p >> 1) * NA + a) * ND) + (p & 1) * 8;
        #pragma unroll
        for (int i = 0; i < ND; i += 256) {
            const int idx = i + tid;
            float2 v = src[SZ(idx)];
            uint32_t u = pkrtz_u32(v.x, v.y);
            float2 vn = src[SZ(min(idx + 1, ND - 1))];
            uint32_t un = pkrtz_u32(vn.x, vn.y);
            *(uint2*)(gb + (size_t)idx * 16) = make_uint2(
                u, h2_to_u32(__hsub2(u32_to_h2(un), u32_to_h2(u))));
        }
    } else {
        uint32_t* __restrict__ yo = packed + ((size_t)(2 * p) * NA + a) * ND;
        #pragma unroll
        for (int i = 0; i < ND; i += 256) {
            float2 v = src[SZ(i + tid)];
            yo[i + tid] = pkrtz_u32(v.x, v.y);
        }
    }
}

// ---------------------------------------------------------------------------
// Kernel 2 (R9): pure-LDS backprojection with DMA staging.
// R8 model (closes to 3%): 64 gather + ~18 staging-write LDS wave-ops per
// CU-angle x ~12 cyc = 984 cyc -> 295us; occupancy doubling didn't lift the
// b128 issue rate (serial pipe). R9 removes the staging ops from the LDS
// issue pipe: wave 0 issues global_load_lds (width 16, VMEM pipe; LDS write
// lands via write ports, no ds_write issue slot, no staging VALU/registers).
// Window padded to WREG=64 entries so each staging op is a full-wave linear
// 1024B transfer (m104: LDS dest = uniform base + lane*16; per-lane global
// src). Schedule: round r consumes bank r&1 (4 angles, 2 ds_read_b128 per
// thread-angle, unchanged); wave0 issues 8 gload_lds for angles 4r+4..4r+7
// into bank (r+1)&1 (freed at round r-1's barrier); wave0-only
// s_waitcnt vmcnt(0) at round end (a full round ~960cyc of latency cover),
// then lgkmcnt(0)+s_barrier. Output bit-identical to R8.
// ---------------------------------------------------------------------------
__global__ __launch_bounds__(256, 8) void backproj_kernel(const uint4* __restrict__ gq,
                                                          const float4* __restrict__ ptable,
                                                          float* __restrict__ img) {
    // win[bank][phase][sg][entry]: 2*4*2*64*16B = 16 KB -> 8 blocks/CU
    __shared__ __align__(16) uint4 win[2][4][2][WREG];

    const int tid = threadIdx.x;
    const int bx = blockIdx.x, by = blockIdx.y, bz = blockIdx.z;

    const float4* __restrict__ pt = ptable + (size_t)((by << 4) + bx) * NA;

    // lane map: wave = 8x x 8y patch; 4 waves tile x
    const int lane = tid & 63;
    const int wid  = tid >> 6;
    const int tx   = (wid << 3) + (lane & 7);
    const int ty   = lane >> 3;                       // 0..7
    const float px  = (float)(bx * TW + tx) - 255.5f;
    const float pyf = (float)(by * TH + ty) - 255.5f;

    // staging sources: quad rows 2bz (sg0: batches 8bz+0..3) and 2bz+1
    // (sg1: batches 8bz+4..7); per-lane global address, linear LDS dest.
    const uint4* __restrict__ q0 = gq + (size_t)(2 * bz) * NA * ND + lane;
    const uint4* __restrict__ q1 = q0 + (size_t)NA * ND;

    float accf[8];
    __half2 hacc01 = u32_to_h2(0u), hacc23 = u32_to_h2(0u),
            hacc45 = u32_to_h2(0u), hacc67 = u32_to_h2(0u);
    #pragma unroll
    for (int b = 0; b < 8; b++) accf[b] = 0.0f;

    auto gld = [](const uint4* g, uint4* l) {
        __builtin_amdgcn_global_load_lds(
            (const __attribute__((address_space(1))) void*)g,
            (__attribute__((address_space(3))) void*)l, 16, 0, 0);
    };
    // stage 4 angles (a..a+3, clamped) into one bank; wave 0 only
    auto stage4 = [&](int a, uint4* bank) {
        #pragma unroll
        for (int j = 0; j < 4; j++) {
            const int off = __float_as_int(pt[min(a + j, NA - 1)].w);
            gld(q0 + off, bank + j * (2 * WREG));
            gld(q1 + off, bank + j * (2 * WREG) + WREG);
        }
    };
    auto consume = [&](float4 P, const uint4* wb, int ph) {
        const float t = fmaf(px, P.x, fmaf(pyf, P.y, P.z));
        const int i0 = (int)t;                    // t > 0 -> trunc == floor
#if __has_builtin(__builtin_amdgcn_fractf)
        float w = __builtin_amdgcn_fractf(t);
#else
        float w = t - (float)i0;
#endif
        __half2 wh2 = u32_to_h2(pkrtz_u32(w, w));     // one pkrtz
        const uint4 qA = wb[ph * 2 * WREG + i0];          // ds_read_b128
        const uint4 qB = wb[ph * 2 * WREG + WREG + i0];   // ds_read_b128
        hacc01 = __hfma2(wh2, u32_to_h2(qA.y), __hadd2(hacc01, u32_to_h2(qA.x)));
        hacc23 = __hfma2(wh2, u32_to_h2(qA.w), __hadd2(hacc23, u32_to_h2(qA.z)));
        hacc45 = __hfma2(wh2, u32_to_h2(qB.y), __hadd2(hacc45, u32_to_h2(qB.x)));
        hacc67 = __hfma2(wh2, u32_to_h2(qB.w), __hadd2(hacc67, u32_to_h2(qB.z)));
    };

    // prologue: stage angles 0..3 into bank0; drain; publish
    if (wid == 0) {
        stage4(0, &win[0][0][0][0]);
        asm volatile("s_waitcnt vmcnt(0)" ::: "memory");
    }
    __builtin_amdgcn_s_barrier();

    #pragma unroll 1
    for (int r = 0; r < NA / 4; ++r) {
        const int a = 4 * r;
        const uint4* wb = &win[r & 1][0][0][0];
        if (wid == 0)
            stage4(a + 4, &win[(r + 1) & 1][0][0][0]);
        const float4 P0 = pt[a],     P1 = pt[a + 1];
        const float4 P2 = pt[a + 2], P3 = pt[a + 3];
        consume(P0, wb, 0);
        consume(P1, wb, 1);
        consume(P2, wb, 2);
        consume(P3, wb, 3);

        // flush fp16 group accumulators into fp32 every 4 rounds (16 angles)
        if ((r & 3) == 3) {
            float2 v01 = __half22float2(hacc01);
            float2 v23 = __half22float2(hacc23);
            float2 v45 = __half22float2(hacc45);
            float2 v67 = __half22float2(hacc67);
            accf[0] += v01.x; accf[1] += v01.y;
            accf[2] += v23.x; accf[3] += v23.y;
            accf[4] += v45.x; accf[5] += v45.y;
            accf[6] += v67.x; accf[7] += v67.y;
            hacc01 = u32_to_h2(0u); hacc23 = u32_to_h2(0u);
            hacc45 = u32_to_h2(0u); hacc67 = u32_to_h2(0u);
        }
        if (wid == 0)
            asm volatile("s_waitcnt vmcnt(0)" ::: "memory");
        asm volatile("s_waitcnt lgkmcnt(0)" ::: "memory");
        __builtin_amdgcn_s_barrier();
    }

    const float SCALE = (float)(M_PI / (double)NA);
    const size_t bstride = (size_t)NH * NW;
    size_t o0 = (((size_t)(bz * NBT) * NH) + (by * TH + ty)) * NW + (bx * TW + tx);
    #pragma unroll
    for (int b = 0; b < 8; b++)
        img[o0 + (size_t)b * bstride] = accf[b] * SCALE;
}

// ---------------------------------------------------------------------------
// Fallback backprojection (R8: register staging from packed rows) — used
// when the workspace cannot hold Gq + ptable.
// ---------------------------------------------------------------------------
#define WINN 36
__global__ __launch_bounds__(256, 8) void backproj_fb(const uint32_t* __restrict__ packed,
                                                      const float4* __restrict__ ptable,
                                                      float* __restrict__ img) {
    __shared__ __align__(16) uint4 win[2][8][WINN];

    const int tid = threadIdx.x;
    const int bx = blockIdx.x, by = blockIdx.y, bz = blockIdx.z;

    const float4* __restrict__ pt = ptable + (size_t)((by << 4) + bx) * NA;

    const bool stg = tid < 2 * WINN;
    const int sg   = (tid >= WINN) ? 1 : 0;
    const int si   = tid - sg * WINN;
    const uint32_t* __restrict__ sbA =
        packed + (size_t)(2 * (4 * bz + 2 * sg)) * NA * ND + si;
    const uint32_t* __restrict__ sbB = sbA + (size_t)2 * NA * ND;
    uint4* const wptr = &win[sg][0][si];

    const int lane = tid & 63;
    const int wid  = tid >> 6;
    const int tx   = (wid << 3) + (lane & 7);
    const int ty   = lane >> 3;
    const float px  = (float)(bx * TW + tx) - 255.5f;
    const float pyf = (float)(by * TH + ty) - 255.5f;

    float accf[8];
    __half2 hacc01 = u32_to_h2(0u), hacc23 = u32_to_h2(0u),
            hacc45 = u32_to_h2(0u), hacc67 = u32_to_h2(0u);
    #pragma unroll
    for (int b = 0; b < 8; b++) accf[b] = 0.0f;

    auto bar = []() {
        asm volatile("s_waitcnt lgkmcnt(0)" ::: "memory");
        __builtin_amdgcn_s_barrier();
    };
    auto stage_load = [&](float4 P, uint2& wA, uint2& wB) {
        const int off = __float_as_int(P.w);
        wA = make_uint2(sbA[off], sbA[off + 1]);
        wB = make_uint2(sbB[off], sbB[off + 1]);
    };
    auto stage_write = [&](int ph, uint2 wA, uint2 wB) {
        wptr[ph * WINN] = make_uint4(
            wA.x, h2_to_u32(__hsub2(u32_to_h2(wA.y), u32_to_h2(wA.x))),
            wB.x, h2_to_u32(__hsub2(u32_to_h2(wB.y), u32_to_h2(wB.x))));
    };
    auto consume = [&](float4 P, int ph) {
        const float t = fmaf(px, P.x, fmaf(pyf, P.y, P.z));
        const int i0 = (int)t;
#if __has_builtin(__builtin_amdgcn_fractf)
        float w = __builtin_amdgcn_fractf(t);
#else
        float w = t - (float)i0;
#endif
        __half2 wh2 = u32_to_h2(pkrtz_u32(w, w));
        const uint4 qA = win[0][ph][i0];
        const uint4 qB = win[1][ph][i0];
        hacc01 = __hfma2(wh2, u32_to_h2(qA.y), __hadd2(hacc01, u32_to_h2(qA.x)));
        hacc23 = __hfma2(wh2, u32_to_h2(qA.w), __hadd2(hacc23, u32_to_h2(qA.z)));
        hacc45 = __hfma2(wh2, u32_to_h2(qB.y), __hadd2(hacc45, u32_to_h2(qB.x)));
        hacc67 = __hfma2(wh2, u32_to_h2(qB.w), __hadd2(hacc67, u32_to_h2(qB.z)));
    };

    uint2 h0A = make_uint2(0, 0), h0B = make_uint2(0, 0);
    uint2 h1A = make_uint2(0, 0), h1B = make_uint2(0, 0);
    uint2 h2A = make_uint2(0, 0), h2B = make_uint2(0, 0);
    uint2 h3A = make_uint2(0, 0), h3B = make_uint2(0, 0);

    if (stg) {
        uint2 wA, wB;
        stage_load(pt[0], wA, wB);  stage_write(0, wA, wB);
        stage_load(pt[1], wA, wB);  stage_write(1, wA, wB);
        stage_load(pt[2], wA, wB);  stage_write(2, wA, wB);
        stage_load(pt[3], wA, wB);  stage_write(3, wA, wB);
        stage_load(pt[4], h0A, h0B);
        stage_load(pt[5], h1A, h1B);
        stage_load(pt[6], h2A, h2B);
        stage_load(pt[7], h3A, h3B);
    }
    bar();

    #pragma unroll 1
    for (int r = 0; r < NA / 4; ++r) {
        const int a = 4 * r;
        const int cb = (r & 1) * 4;
        const int ob = cb ^ 4;
        const float4 P0 = pt[a],     P1 = pt[a + 1];
        const float4 P2 = pt[a + 2], P3 = pt[a + 3];

        if (stg) {
            stage_write(ob + 0, h0A, h0B);
            stage_write(ob + 1, h1A, h1B);
            stage_write(ob + 2, h2A, h2B);
            stage_write(ob + 3, h3A, h3B);
            stage_load(pt[min(a + 8,  NA - 1)], h0A, h0B);
            stage_load(pt[min(a + 9,  NA - 1)], h1A, h1B);
            stage_load(pt[min(a + 10, NA - 1)], h2A, h2B);
            stage_load(pt[min(a + 11, NA - 1)], h3A, h3B);
        }
        consume(P0, cb + 0);
        consume(P1, cb + 1);
        consume(P2, cb + 2);
        consume(P3, cb + 3);

        if ((r & 3) == 3) {
            float2 v01 = __half22float2(hacc01);
            float2 v23 = __half22float2(hacc23);
            float2 v45 = __half22float2(hacc45);
            float2 v67 = __half22float2(hacc67);
            accf[0] += v01.x; accf[1] += v01.y;
            accf[2] += v23.x; accf[3] += v23.y;
            accf[4] += v45.x; accf[5] += v45.y;
            accf[6] += v67.x; accf[7] += v67.y;
            hacc01 = u32_to_h2(0u); hacc23 = u32_to_h2(0u);
            hacc45 = u32_to_h2(0u); hacc67 = u32_to_h2(0u);
        }
        bar();
    }

    const float SCALE = (float)(M_PI / (double)NA);
    const size_t bstride = (size_t)NH * NW;
    size_t o0 = (((size_t)(bz * NBT) * NH) + (by * TH + ty)) * NW + (bx * TW + tx);
    #pragma unroll
    for (int b = 0; b < 8; b++)
        img[o0 + (size_t)b * bstride] = accf[b] * SCALE;
}

// ---------------------------------------------------------------------------
extern "C" void kernel_launch(void* const* d_in, const int* in_sizes, int n_in,
                              void* d_out, int out_size, void* d_ws, size_t ws_size,
                              hipStream_t stream) {
    const float* sino = (const float*)d_in[0];
    const float* filt = (const float*)d_in[1];
    float* out = (float*)d_out;

    const size_t gq_bytes   = (size_t)4 * NA * ND * sizeof(uint4);       // 47.2 MB
    const size_t ptab_bytes = (size_t)1024 * NA * sizeof(float4);        // 11.8 MB
    const size_t twg_bytes  = (size_t)768 * sizeof(float2);              //  6 KB

    if (ws_size >= gq_bytes + ptab_bytes + twg_bytes) {
        uint4*  gq     = (uint4*)d_ws;
        float4* ptable = (float4*)((char*)d_ws + gq_bytes);
        float2* twg    = (float2*)((char*)d_ws + gq_bytes + ptab_bytes);
        prep_kernel<<<dim3(1025), dim3(768), 0, stream>>>(ptable, twg);
        filter_kernel<<<dim3(NA, NB / 2), dim3(256), 0, stream>>>(sino, filt, twg, gq, nullptr);
        backproj_kernel<<<dim3(NW / TW, NH / TH, NB / NBT), dim3(256), 0, stream>>>(gq, ptable, out);
    } else {
        // fallback: pack fp16 rows in-place into the input (block-local
        // writes); ptable + twiddles in d_ws; R8 register-staging backproj.
        uint32_t* packed = (uint32_t*)d_in[0];
        float4* ptable   = (float4*)d_ws;
        float2* twg      = (float2*)((char*)d_ws + ptab_bytes);
        prep_kernel<<<dim3(1025), dim3(768), 0, stream>>>(ptable, twg);
        filter_kernel<<<dim3(NA, NB / 2), dim3(256), 0, stream>>>(sino, filt, twg, nullptr, packed);
        backproj_fb<<<dim3(NW / TW, NH / TH, NB / NBT), dim3(256), 0, stream>>>(packed, ptable, out);
    }
}